// Round 2
// baseline (294.650 us; speedup 1.0000x reference)
//
#include <hip/hip_runtime.h>
#include <math.h>

#define NSEQ 2048
#define CDIM 768
#define NH   12
#define HD   64
#define NB   2

typedef unsigned short u16;
typedef __attribute__((ext_vector_type(8))) short bf16x8;   // 8 bf16 = 4 VGPRs
typedef __attribute__((ext_vector_type(4))) float f32x4;
typedef __attribute__((ext_vector_type(8))) float f32x8;
typedef __attribute__((ext_vector_type(4))) __bf16 bf16x4t;
typedef __attribute__((ext_vector_type(8))) __bf16 bf16x8t;

// fp32 -> bf16 round-to-nearest-even (scalar epilogue paths)
__device__ __forceinline__ u16 f2bf(float x) {
    unsigned int u = __float_as_uint(x);
    u += 0x7fffu + ((u >> 16) & 1u);
    return (u16)(u >> 16);
}

// pack 8 fp32 -> 8 bf16 via compiler-generated v_cvt_pk_bf16_f32
__device__ __forceinline__ uint4 pack8(float4 a, float4 b) {
    f32x8 v = {a.x, a.y, a.z, a.w, b.x, b.y, b.z, b.w};
    union { bf16x8t t; uint4 u; } o;
    o.t = __builtin_convertvector(v, bf16x8t);
    return o.u;
}

#define LSTR 72   // LDS row stride (u16) for the GEMM kernels (+8 pad)

// async global->LDS, 16B per lane, LDS dest = wave-uniform base + lane*16
#define GLD16(gp, lp) __builtin_amdgcn_global_load_lds( \
    (__attribute__((address_space(1))) void*)(const void*)(gp), \
    (__attribute__((address_space(3))) void*)(void*)(lp), 16, 0, 0)

// ---------------------------------------------------------------------------
// Kernel 1: qkv = X @ Wqkv^T, bf16 MFMA, fp32 inputs converted in-register
// during staging. Tiles 128x128x64, 4 waves 2x2. R10: (a) LDS double-buffer
// -> ONE barrier per K-step; next-tile LDS write happens AFTER the MFMA
// phase so the global-load wait overlaps compute. (b) bijective XCD swizzle
// groups blocks by W-column band (~1MB Wqkv per XCD -> L2-resident).
// Q,K: [B,H,N,64]; V: [B,H,64,N] (transposed for attn B-fragments).
// Grid: 1D 576.
// ---------------------------------------------------------------------------
__global__ __launch_bounds__(256)
void qkv_mfma_kernel(const float* __restrict__ Xf, const float* __restrict__ Wf,
                     u16* __restrict__ Qb, u16* __restrict__ Kb,
                     u16* __restrict__ Vb)
{
    __shared__ __align__(16) u16 S[4 * 128 * LSTR];   // 2 bufs x (A+B), 72KB

    const int tid  = threadIdx.x;
    const int lane = tid & 63;
    const int wid  = tid >> 6;
    const int l15  = lane & 15;
    const int quad = lane >> 4;
    const int wr = wid >> 1, wc = wid & 1;

    // XCD swizzle: xcd = f&7 owns 72 consecutive blocks in n-major order
    // -> each XCD sees a ~2.25-row W band (~1.1MB fp32) that stays in its L2.
    const int f   = blockIdx.x;
    const int L   = (f & 7) * 72 + (f >> 3);
    const int m0  = (L & 31) * 128;
    const int n0  = (L >> 5) * 128;

    const int row = tid >> 3, c8s = (tid & 7) << 3;   // 8-u16 chunk coords

    f32x4 acc[4][4];
#pragma unroll
    for (int mi = 0; mi < 4; ++mi)
#pragma unroll
        for (int ni = 0; ni < 4; ++ni)
            acc[mi][ni] = (f32x4){0.f, 0.f, 0.f, 0.f};

    float4 pa[4][2], pb[4][2];
#pragma unroll
    for (int it = 0; it < 4; ++it) {
        size_t ga = (size_t)(m0 + row + 32 * it) * CDIM + c8s;
        size_t gb = (size_t)(n0 + row + 32 * it) * CDIM + c8s;
        pa[it][0] = *(const float4*)&Xf[ga];
        pa[it][1] = *(const float4*)&Xf[ga + 4];
        pb[it][0] = *(const float4*)&Wf[gb];
        pb[it][1] = *(const float4*)&Wf[gb + 4];
    }

    // prologue: write buffer 0
    {
        u16* As = S;
        u16* Bs = S + 128 * LSTR;
#pragma unroll
        for (int it = 0; it < 4; ++it) {
            *(uint4*)&As[(row + 32 * it) * LSTR + c8s] =
                pack8(pa[it][0], pa[it][1]);
            *(uint4*)&Bs[(row + 32 * it) * LSTR + c8s] =
                pack8(pb[it][0], pb[it][1]);
        }
    }
    __syncthreads();

    int cur = 0;
    for (int kt = 0; kt < CDIM; kt += 64) {
        const u16* Ac = S + cur * (2 * 128 * LSTR);
        const u16* Bc = Ac + 128 * LSTR;
        const bool more = (kt + 64 < CDIM);

        if (more) {
#pragma unroll
            for (int it = 0; it < 4; ++it) {
                size_t ga = (size_t)(m0 + row + 32 * it) * CDIM + kt + 64 + c8s;
                size_t gb = (size_t)(n0 + row + 32 * it) * CDIM + kt + 64 + c8s;
                pa[it][0] = *(const float4*)&Xf[ga];
                pa[it][1] = *(const float4*)&Xf[ga + 4];
                pb[it][0] = *(const float4*)&Wf[gb];
                pb[it][1] = *(const float4*)&Wf[gb + 4];
            }
        }

#pragma unroll
        for (int k = 0; k < 2; ++k) {
            bf16x8 af[4];
#pragma unroll
            for (int mi = 0; mi < 4; ++mi)
                af[mi] = *(const bf16x8*)
                    &Ac[(wr * 64 + mi * 16 + l15) * LSTR + quad * 8 + 32 * k];
#pragma unroll
            for (int ni = 0; ni < 4; ++ni) {
                bf16x8 bfr = *(const bf16x8*)
                    &Bc[(wc * 64 + ni * 16 + l15) * LSTR + quad * 8 + 32 * k];
#pragma unroll
                for (int mi = 0; mi < 4; ++mi)
                    acc[mi][ni] = __builtin_amdgcn_mfma_f32_16x16x32_bf16(
                        af[mi], bfr, acc[mi][ni], 0, 0, 0);
            }
        }

        if (more) {
            u16* An = S + (cur ^ 1) * (2 * 128 * LSTR);
            u16* Bn = An + 128 * LSTR;
#pragma unroll
            for (int it = 0; it < 4; ++it) {
                *(uint4*)&An[(row + 32 * it) * LSTR + c8s] =
                    pack8(pa[it][0], pa[it][1]);
                *(uint4*)&Bn[(row + 32 * it) * LSTR + c8s] =
                    pack8(pb[it][0], pb[it][1]);
            }
        }
        __syncthreads();
        cur ^= 1;
    }

    // Epilogue (Ew lives in buffer-0 region; last MFMA reads were buffer 1,
    // and the loop's final barrier already separates). C-layout: token row =
    // wr*64+mi*16+quad*4+r, feature col = wc*64+ni*16+l15.
    const int bi      = m0 >> 11;
    const int nbase   = (m0 & 2047) + wr * 64;
    const int colbase = n0 + wc * 64;
    const int sel     = colbase / CDIM;          // 0=q,1=k,2=v (wave-uniform)
    const int h       = (colbase % CDIM) >> 6;

    u16* Ew = S + wid * 64 * LSTR;     // wave-private 64x72 tile
    const int grow = lane >> 3;        // copy-out: 8 lanes cover one 128B row
    const int gc8  = (lane & 7) << 3;

    if (sel == 2) {
#pragma unroll
        for (int ni = 0; ni < 4; ++ni)
#pragma unroll
            for (int mi = 0; mi < 4; ++mi)
#pragma unroll
                for (int r = 0; r < 4; ++r)
                    Ew[(ni * 16 + l15) * LSTR + mi * 16 + quad * 4 + r] =
                        f2bf(acc[mi][ni][r]);
        u16* dst = Vb + (size_t)(bi * NH + h) * HD * NSEQ;   // [64][2048]
#pragma unroll
        for (int it = 0; it < 8; ++it) {
            int dd = grow + 8 * it;
            *(uint4*)&dst[(size_t)dd * NSEQ + nbase + gc8] =
                *(const uint4*)&Ew[dd * LSTR + gc8];
        }
    } else {
        u16* dst = ((sel == 0) ? Qb : Kb) + (size_t)(bi * NH + h) * NSEQ * HD;
        const float scl = (sel == 0) ? 0.125f : 1.0f;
#pragma unroll
        for (int ni = 0; ni < 4; ++ni) {
            int dd = ni * 16 + l15;
            float invf = expf(-0.14391156831212787f * (float)(dd & ~1));
#pragma unroll
            for (int mi = 0; mi < 4; ++mi) {
                f32x4 val = acc[mi][ni];
#pragma unroll
                for (int r = 0; r < 4; ++r) {
                    float e = val[r] * scl;
                    float p = __shfl_xor(e, 1);    // pair partner (col^1)
                    int n = nbase + mi * 16 + quad * 4 + r;
                    float sv, cv;
                    __sincosf((float)n * invf, &sv, &cv);
                    float o = (dd & 1) ? (e * cv + p * sv)
                                       : (e * cv - p * sv);
                    Ew[(mi * 16 + quad * 4 + r) * LSTR + dd] = f2bf(o);
                }
            }
        }
#pragma unroll
        for (int it = 0; it < 8; ++it) {
            int tr = grow + 8 * it;
            *(uint4*)&dst[(size_t)(nbase + tr) * HD + gc8] =
                *(const uint4*)&Ew[tr * LSTR + gc8];
        }
    }
}

// ---------------------------------------------------------------------------
// Kernel 2: flash attention, bf16 MFMA. S^T orientation, fixed-max softmax.
// R10: K+V per (b,h) is 512KB -> L2-fits (Common-mistake #7: don't stage
// what caches). K/V fragments are read DIRECTLY from global each tile; the
// only LDS is the wave-private P transpose tile (8KB). Zero barriers —
// the 4 waves run fully independently (s_setprio pays here, m191). A
// bijective XCD swizzle pins each (b,h)'s 32 query-blocks to ONE XCD so
// K/V re-reads are L2 hits (3 bh x 512KB = 1.5MB per XCD L2).
// Grid: 1D 768.
// ---------------------------------------------------------------------------
__global__ __launch_bounds__(256)
void attn_kernel(const u16* __restrict__ Qb, const u16* __restrict__ Kb,
                 const u16* __restrict__ Vt, u16* __restrict__ AO)
{
    __shared__ __align__(16) u16 Ps[4][16 * 64];   // wave-private P tiles

    const int tid  = threadIdx.x;
    const int lane = tid & 63;
    const int wid  = tid >> 6;
    const int l15  = lane & 15;
    const int quad = lane >> 4;
    const int swz  = (l15 & 7) << 3;   // XOR swizzle for P writes/reads

    // XCD swizzle: xcd = f&7 -> bh in {3*xcd .. 3*xcd+2}; 96 blocks/XCD.
    const int f  = blockIdx.x;
    const int i  = f >> 3;
    const int bh = (f & 7) * 3 + (i >> 5);   // 0..23
    const int qt = i & 31;                   // 0..31

    const u16* Qg = Qb + ((size_t)bh * NSEQ + qt * 64) * HD;
    const u16* Kg = Kb + (size_t)bh * NSEQ * HD;
    const u16* Vg = Vt + (size_t)bh * HD * NSEQ;   // [64][2048]

    // Q fragments straight from global (rows are 128B; one-time read)
    bf16x8 aq[2];
    aq[0] = *(const bf16x8*)&Qg[(wid * 16 + l15) * HD + quad * 8];
    aq[1] = *(const bf16x8*)&Qg[(wid * 16 + l15) * HD + quad * 8 + 32];

    union { u16 s[8]; bf16x8 v; } oneu;
#pragma unroll
    for (int ii = 0; ii < 8; ++ii) oneu.s[ii] = 0x3f80;   // bf16 1.0
    const bf16x8 vone = oneu.v;

    f32x4 O[4];
#pragma unroll
    for (int t = 0; t < 4; ++t) O[t] = (f32x4){0.f, 0.f, 0.f, 0.f};
    f32x4 lacc = (f32x4){0.f, 0.f, 0.f, 0.f};   // softmax denominator rows

    u16* Pw = Ps[wid];

    for (int kt = 0; kt < NSEQ / 64; ++kt) {
        const u16* Kt = Kg + (size_t)(kt << 6) * HD;
        const u16* Vp = Vg + (kt << 6);

        // issue all 16 K/V fragment loads up front; QK^T covers bv latency
        bf16x8 ak0[4], ak1[4], bv0[4], bv1[4];
#pragma unroll
        for (int mt = 0; mt < 4; ++mt) {
            ak0[mt] = *(const bf16x8*)&Kt[(mt * 16 + l15) * HD + quad * 8];
            ak1[mt] = *(const bf16x8*)&Kt[(mt * 16 + l15) * HD + quad * 8 + 32];
        }
#pragma unroll
        for (int t = 0; t < 4; ++t) {
            bv0[t] = *(const bf16x8*)&Vp[(size_t)(t * 16 + l15) * NSEQ + quad * 8];
            bv1[t] = *(const bf16x8*)&Vp[(size_t)(t * 16 + l15) * NSEQ + quad * 8 + 32];
        }

        // S^T = K . Q^T : D[key=mt*16+quad*4+r][qrow=l15]
        f32x4 sacc[4];
#pragma unroll
        for (int mt = 0; mt < 4; ++mt) sacc[mt] = (f32x4){0.f, 0.f, 0.f, 0.f};
        __builtin_amdgcn_s_setprio(1);
#pragma unroll
        for (int mt = 0; mt < 4; ++mt)
            sacc[mt] = __builtin_amdgcn_mfma_f32_16x16x32_bf16(
                ak0[mt], aq[0], sacc[mt], 0, 0, 0);
#pragma unroll
        for (int mt = 0; mt < 4; ++mt)
            sacc[mt] = __builtin_amdgcn_mfma_f32_16x16x32_bf16(
                ak1[mt], aq[1], sacc[mt], 0, 0, 0);
        __builtin_amdgcn_s_setprio(0);

        // fixed-max softmax, in-lane; P -> wave-private LDS (transpose)
#pragma unroll
        for (int mt = 0; mt < 4; ++mt) {
            f32x4 ev;
#pragma unroll
            for (int r = 0; r < 4; ++r) ev[r] = __expf(sacc[mt][r]);
            bf16x4t pbk = __builtin_convertvector(ev, bf16x4t);
            *(bf16x4t*)&Pw[l15 * 64 + ((mt * 16 + quad * 4) ^ swz)] = pbk;
        }
        bf16x8 ap0 = *(const bf16x8*)&Pw[l15 * 64 + ((quad * 8) ^ swz)];
        bf16x8 ap1 = *(const bf16x8*)&Pw[l15 * 64 + ((quad * 8 + 32) ^ swz)];

        // O += P . V ; denominator via ones-fragment MFMA
        __builtin_amdgcn_s_setprio(1);
        lacc = __builtin_amdgcn_mfma_f32_16x16x32_bf16(ap0, vone, lacc, 0, 0, 0);
#pragma unroll
        for (int t = 0; t < 4; ++t)
            O[t] = __builtin_amdgcn_mfma_f32_16x16x32_bf16(
                ap0, bv0[t], O[t], 0, 0, 0);
        lacc = __builtin_amdgcn_mfma_f32_16x16x32_bf16(ap1, vone, lacc, 0, 0, 0);
#pragma unroll
        for (int t = 0; t < 4; ++t)
            O[t] = __builtin_amdgcn_mfma_f32_16x16x32_bf16(
                ap1, bv1[t], O[t], 0, 0, 0);
        __builtin_amdgcn_s_setprio(0);
    }

    // lacc[r] = sum_k P for qrow quad*4+r — same row layout as O[t][r]
    float inv4[4];
#pragma unroll
    for (int r = 0; r < 4; ++r) inv4[r] = 1.0f / lacc[r];

    const int b = bh / NH, h = bh % NH;
#pragma unroll
    for (int r = 0; r < 4; ++r) {
        size_t orow = (size_t)b * NSEQ + qt * 64 + wid * 16 + quad * 4 + r;
#pragma unroll
        for (int t = 0; t < 4; ++t)
            AO[orow * CDIM + h * HD + t * 16 + l15] = f2bf(O[t][r] * inv4[r]);
    }
}

// ---------------------------------------------------------------------------
// Kernel 3: out = AO @ Wproj^T + bias, bf16 MFMA. 64x64 tiles, grid 768
// (3 blocks/CU). A staged via global_load_lds with source-side XOR swizzle;
// W converted fp32->bf16 with cvt_pk during staging. R10: XCD swizzle
// groups blocks by W-band (~300KB per XCD -> L2-resident).
// ---------------------------------------------------------------------------
__global__ __launch_bounds__(256)
void proj_kernel(const u16* __restrict__ A, const float* __restrict__ Wf,
                 const float* __restrict__ bias, float* __restrict__ out)
{
    __shared__ __align__(16) u16 As[64 * 64];
    __shared__ __align__(16) u16 Bs[64 * 64];
    const int tid  = threadIdx.x;
    const int lane = tid & 63;
    const int wid  = tid >> 6;
    const int l15  = lane & 15;
    const int quad = lane >> 4;
    const int swz  = (l15 & 7) << 3;
    const int wr = wid >> 1, wc = wid & 1;

    // XCD swizzle: 96 blocks/XCD in n-major order -> ~1.5 n-rows per XCD
    const int fb = blockIdx.x;
    const int L  = (fb & 7) * 96 + (fb >> 3);
    const int m0 = (L & 63) * 64;
    const int n0 = (L >> 6) * 64;

    const int r0 = tid >> 3;                        // 0..31
    const int cs = ((tid & 7) ^ (r0 & 7)) << 3;     // swizzled A source col
    const int c8 = (tid & 7) << 3;
    const int bswz = c8 ^ ((r0 & 7) << 3);          // swizzled B dest col

    f32x4 acc[2][2];
#pragma unroll
    for (int mi = 0; mi < 2; ++mi)
#pragma unroll
        for (int ni = 0; ni < 2; ++ni)
            acc[mi][ni] = (f32x4){0.f, 0.f, 0.f, 0.f};

    for (int kt = 0; kt < CDIM; kt += 64) {
        __syncthreads();
        // A: 64x64 bf16 tile, async direct-to-LDS (chunks tid, tid+256)
        GLD16(A + ((size_t)(m0 + r0) * CDIM + kt + cs),      &As[wid * 512]);
        GLD16(A + ((size_t)(m0 + r0 + 32) * CDIM + kt + cs), &As[wid * 512 + 2048]);
        // B: 64x64 fp32 -> bf16, swizzled register-staged write
        {
            size_t gb0 = (size_t)(n0 + r0) * CDIM + kt + c8;
            size_t gb1 = (size_t)(n0 + r0 + 32) * CDIM + kt + c8;
            float4 w0 = *(const float4*)&Wf[gb0];
            float4 w1 = *(const float4*)&Wf[gb0 + 4];
            float4 w2 = *(const float4*)&Wf[gb1];
            float4 w3 = *(const float4*)&Wf[gb1 + 4];
            *(uint4*)&Bs[r0 * 64 + bswz]        = pack8(w0, w1);
            *(uint4*)&Bs[(r0 + 32) * 64 + bswz] = pack8(w2, w3);
        }
        __syncthreads();

#pragma unroll
        for (int k = 0; k < 2; ++k) {
            bf16x8 af[2], bf[2];
#pragma unroll
            for (int mi = 0; mi < 2; ++mi)
                af[mi] = *(const bf16x8*)
                    &As[(wr * 32 + mi * 16 + l15) * 64 + ((quad * 8 + 32 * k) ^ swz)];
#pragma unroll
            for (int ni = 0; ni < 2; ++ni)
                bf[ni] = *(const bf16x8*)
                    &Bs[(wc * 32 + ni * 16 + l15) * 64 + ((quad * 8 + 32 * k) ^ swz)];
#pragma unroll
            for (int mi = 0; mi < 2; ++mi)
#pragma unroll
                for (int ni = 0; ni < 2; ++ni)
                    acc[mi][ni] = __builtin_amdgcn_mfma_f32_16x16x32_bf16(
                        af[mi], bf[ni], acc[mi][ni], 0, 0, 0);
        }
    }

#pragma unroll
    for (int ni = 0; ni < 2; ++ni) {
        int col = n0 + wc * 32 + ni * 16 + l15;
        float bb = bias[col];
#pragma unroll
        for (int mi = 0; mi < 2; ++mi) {
            int rw = m0 + wr * 32 + mi * 16 + quad * 4;
#pragma unroll
            for (int r = 0; r < 4; ++r)
                out[(size_t)(rw + r) * CDIM + col] = acc[mi][ni][r] + bb;
        }
    }
}

// ---------------------------------------------------------------------------
extern "C" void kernel_launch(void* const* d_in, const int* in_sizes, int n_in,
                              void* d_out, int out_size, void* d_ws,
                              size_t ws_size, hipStream_t stream)
{
    const float* X     = (const float*)d_in[0];   // [2, 2048, 768]
    const float* Wqkv  = (const float*)d_in[1];   // [2304, 768]
    const float* Wproj = (const float*)d_in[2];   // [768, 768]
    const float* bias  = (const float*)d_in[3];   // [768]
    float* out = (float*)d_out;                   // [2, 2048, 768]

    const size_t per_buf = (size_t)NB * NH * NSEQ * HD;   // 3145728
    u16* Qb  = (u16*)d_ws;
    u16* Kb  = Qb + per_buf;
    u16* Vb  = Kb + per_buf;                      // [B,H,64,N]
    u16* AOb = Vb + per_buf;                      // [4096, 768] bf16

    qkv_mfma_kernel<<<dim3(576), 256, 0, stream>>>(X, Wqkv, Qb, Kb, Vb);
    attn_kernel<<<dim3(768), 256, 0, stream>>>(Qb, Kb, Vb, AOb);
    proj_kernel<<<dim3(768), 256, 0, stream>>>(AOb, Wproj, bias, out);
}

// Round 3
// 172.198 us; speedup vs baseline: 1.7111x; 1.7111x over previous
//
#include <hip/hip_runtime.h>
#include <math.h>

#define NSEQ 2048
#define CDIM 768
#define NH   12
#define HD   64
#define NB   2

typedef unsigned short u16;
typedef __attribute__((ext_vector_type(8))) short bf16x8;   // 8 bf16 = 4 VGPRs
typedef __attribute__((ext_vector_type(4))) float f32x4;
typedef __attribute__((ext_vector_type(8))) float f32x8;
typedef __attribute__((ext_vector_type(4))) __bf16 bf16x4t;
typedef __attribute__((ext_vector_type(8))) __bf16 bf16x8t;

// fp32 -> bf16 round-to-nearest-even (scalar epilogue paths)
__device__ __forceinline__ u16 f2bf(float x) {
    unsigned int u = __float_as_uint(x);
    u += 0x7fffu + ((u >> 16) & 1u);
    return (u16)(u >> 16);
}

// pack 8 fp32 -> 8 bf16 via compiler-generated v_cvt_pk_bf16_f32
__device__ __forceinline__ uint4 pack8(float4 a, float4 b) {
    f32x8 v = {a.x, a.y, a.z, a.w, b.x, b.y, b.z, b.w};
    union { bf16x8t t; uint4 u; } o;
    o.t = __builtin_convertvector(v, bf16x8t);
    return o.u;
}

#define LSTR 72   // LDS row stride (u16) for the GEMM kernels (+8 pad)

// async global->LDS, 16B per lane, LDS dest = wave-uniform base + lane*16
#define GLD16(gp, lp) __builtin_amdgcn_global_load_lds( \
    (__attribute__((address_space(1))) void*)(const void*)(gp), \
    (__attribute__((address_space(3))) void*)(void*)(lp), 16, 0, 0)

// ---------------------------------------------------------------------------
// Kernel 1: qkv = X @ Wqkv^T, bf16 MFMA, fp32 inputs converted in-register
// during staging (R1-proven version). Tiles 128x128x64, 4 waves 2x2,
// register-prefetch staging, LDS epilogue with full-128B-line stores.
// Fused scale (q), RoPE (q,k). Q,K: [B,H,N,64]; V: [B,H,64,N].
// ---------------------------------------------------------------------------
__global__ __launch_bounds__(256)
void qkv_mfma_kernel(const float* __restrict__ Xf, const float* __restrict__ Wf,
                     u16* __restrict__ Qb, u16* __restrict__ Kb,
                     u16* __restrict__ Vb)
{
    __shared__ __align__(16) u16 S[2 * 128 * LSTR];
    u16* As = S;
    u16* Bs = S + 128 * LSTR;

    const int tid  = threadIdx.x;
    const int lane = tid & 63;
    const int wid  = tid >> 6;
    const int l15  = lane & 15;
    const int quad = lane >> 4;
    const int wr = wid >> 1, wc = wid & 1;
    const int m0 = blockIdx.x * 128;
    const int n0 = blockIdx.y * 128;

    const int row = tid >> 3, c8s = (tid & 7) << 3;   // 8-u16 chunk coords

    f32x4 acc[4][4];
#pragma unroll
    for (int mi = 0; mi < 4; ++mi)
#pragma unroll
        for (int ni = 0; ni < 4; ++ni)
            acc[mi][ni] = (f32x4){0.f, 0.f, 0.f, 0.f};

    float4 pa[4][2], pb[4][2];
#pragma unroll
    for (int it = 0; it < 4; ++it) {
        size_t ga = (size_t)(m0 + row + 32 * it) * CDIM + c8s;
        size_t gb = (size_t)(n0 + row + 32 * it) * CDIM + c8s;
        pa[it][0] = *(const float4*)&Xf[ga];
        pa[it][1] = *(const float4*)&Xf[ga + 4];
        pb[it][0] = *(const float4*)&Wf[gb];
        pb[it][1] = *(const float4*)&Wf[gb + 4];
    }

    for (int kt = 0; kt < CDIM; kt += 64) {
        __syncthreads();
#pragma unroll
        for (int it = 0; it < 4; ++it) {
            *(uint4*)&As[(row + 32 * it) * LSTR + c8s] =
                pack8(pa[it][0], pa[it][1]);
            *(uint4*)&Bs[(row + 32 * it) * LSTR + c8s] =
                pack8(pb[it][0], pb[it][1]);
        }
        __syncthreads();

        if (kt + 64 < CDIM) {
#pragma unroll
            for (int it = 0; it < 4; ++it) {
                size_t ga = (size_t)(m0 + row + 32 * it) * CDIM + kt + 64 + c8s;
                size_t gb = (size_t)(n0 + row + 32 * it) * CDIM + kt + 64 + c8s;
                pa[it][0] = *(const float4*)&Xf[ga];
                pa[it][1] = *(const float4*)&Xf[ga + 4];
                pb[it][0] = *(const float4*)&Wf[gb];
                pb[it][1] = *(const float4*)&Wf[gb + 4];
            }
        }

#pragma unroll
        for (int k = 0; k < 2; ++k) {
            bf16x8 af[4];
#pragma unroll
            for (int mi = 0; mi < 4; ++mi)
                af[mi] = *(const bf16x8*)
                    &As[(wr * 64 + mi * 16 + l15) * LSTR + quad * 8 + 32 * k];
#pragma unroll
            for (int ni = 0; ni < 4; ++ni) {
                bf16x8 bfr = *(const bf16x8*)
                    &Bs[(wc * 64 + ni * 16 + l15) * LSTR + quad * 8 + 32 * k];
#pragma unroll
                for (int mi = 0; mi < 4; ++mi)
                    acc[mi][ni] = __builtin_amdgcn_mfma_f32_16x16x32_bf16(
                        af[mi], bfr, acc[mi][ni], 0, 0, 0);
            }
        }
    }

    __syncthreads();   // all waves done reading As/Bs before overlay

    // Epilogue. C-layout: token row = wr*64+mi*16+quad*4+r,
    // feature col = wc*64+ni*16+l15. Wave's 64 cols = exactly one head.
    const int bi      = m0 >> 11;
    const int nbase   = (m0 & 2047) + wr * 64;
    const int colbase = n0 + wc * 64;
    const int sel     = colbase / CDIM;          // 0=q,1=k,2=v (wave-uniform)
    const int h       = (colbase % CDIM) >> 6;

    u16* Ew = S + wid * 64 * LSTR;     // wave-private 64x72 tile
    const int grow = lane >> 3;        // copy-out: 8 lanes cover one 128B row
    const int gc8  = (lane & 7) << 3;

    if (sel == 2) {
#pragma unroll
        for (int ni = 0; ni < 4; ++ni)
#pragma unroll
            for (int mi = 0; mi < 4; ++mi)
#pragma unroll
                for (int r = 0; r < 4; ++r)
                    Ew[(ni * 16 + l15) * LSTR + mi * 16 + quad * 4 + r] =
                        f2bf(acc[mi][ni][r]);
        u16* dst = Vb + (size_t)(bi * NH + h) * HD * NSEQ;   // [64][2048]
#pragma unroll
        for (int it = 0; it < 8; ++it) {
            int dd = grow + 8 * it;
            *(uint4*)&dst[(size_t)dd * NSEQ + nbase + gc8] =
                *(const uint4*)&Ew[dd * LSTR + gc8];
        }
    } else {
        u16* dst = ((sel == 0) ? Qb : Kb) + (size_t)(bi * NH + h) * NSEQ * HD;
        const float scl = (sel == 0) ? 0.125f : 1.0f;
#pragma unroll
        for (int ni = 0; ni < 4; ++ni) {
            int dd = ni * 16 + l15;
            float invf = expf(-0.14391156831212787f * (float)(dd & ~1));
#pragma unroll
            for (int mi = 0; mi < 4; ++mi) {
                f32x4 val = acc[mi][ni];
#pragma unroll
                for (int r = 0; r < 4; ++r) {
                    float e = val[r] * scl;
                    float p = __shfl_xor(e, 1);    // pair partner (col^1)
                    int n = nbase + mi * 16 + quad * 4 + r;
                    float sv, cv;
                    __sincosf((float)n * invf, &sv, &cv);
                    float o = (dd & 1) ? (e * cv + p * sv)
                                       : (e * cv - p * sv);
                    Ew[(mi * 16 + quad * 4 + r) * LSTR + dd] = f2bf(o);
                }
            }
        }
#pragma unroll
        for (int it = 0; it < 8; ++it) {
            int tr = grow + 8 * it;
            *(uint4*)&dst[(size_t)(nbase + tr) * HD + gc8] =
                *(const uint4*)&Ew[tr * LSTR + gc8];
        }
    }
}

// ---------------------------------------------------------------------------
// Kernel 2: flash attention, bf16 MFMA. R11: R2's direct-global fragment
// reads regressed 3.6x (16 strided lines per load instr = 16x L2 request
// cost) -> fragments MUST come from LDS. But R1 was LDS-BW-bound: all 4
// waves read IDENTICAL K/V fragments (addresses independent of wid) ->
// 4x redundant LDS traffic. Fix: 32 q-rows per wave (2 q-groups), 2-wave
// 128-thread blocks -> each K/V fragment read feeds 2 MFMAs; block-iter
// LDS volume 96KB -> 64KB per 64 q-rows. Keeps: gload_lds staging with
// source-side XOR swizzle (rule 21), K/V double-buffer + ONE barrier/iter,
// ones-MFMA softmax denominator, XCD bh-pinning, setprio on MFMA clusters.
// LDS 40KB -> 4 blocks/CU. Grid: 1D 768 (x128 threads).
// ---------------------------------------------------------------------------
#define STAGE_KV(BUF, kt_) do {                                               \
    _Pragma("unroll")                                                         \
    for (int k_ = 0; k_ < 4; ++k_) {                                          \
        GLD16(Kg + ((size_t)(((kt_) << 6) + r0 + 16 * k_) * HD + cs),         \
              &Ks[BUF][wid * 512 + 1024 * k_]);                               \
        GLD16(Vg + ((size_t)(r0 + 16 * k_) * NSEQ + ((kt_) << 6) + cs),       \
              &Vs[BUF][wid * 512 + 1024 * k_]);                               \
    }                                                                         \
} while (0)

__global__ __launch_bounds__(128)
void attn_kernel(const u16* __restrict__ Qb, const u16* __restrict__ Kb,
                 const u16* __restrict__ Vt, u16* __restrict__ AO)
{
    __shared__ __align__(16) u16 Ks[2][64 * 64];   // 16KB
    __shared__ __align__(16) u16 Vs[2][64 * 64];   // 16KB  [d][key]
    __shared__ __align__(16) u16 Ps[2][2][16 * 64]; // 8KB: [wave][qg]

    const int tid  = threadIdx.x;      // 0..127
    const int lane = tid & 63;
    const int wid  = tid >> 6;         // 0..1
    const int l15  = lane & 15;
    const int quad = lane >> 4;
    const int swz  = (l15 & 7) << 3;   // XOR swizzle for frag reads/P ops

    // XCD swizzle: xcd = f&7 -> bh in {3*xcd .. 3*xcd+2}; 96 blocks/XCD.
    const int f  = blockIdx.x;
    const int i  = f >> 3;
    const int bh = (f & 7) * 3 + (i >> 5);   // 0..23
    const int qt = i & 31;                   // 0..31

    const u16* Qg = Qb + ((size_t)bh * NSEQ + qt * 64) * HD;
    const u16* Kg = Kb + (size_t)bh * NSEQ * HD;
    const u16* Vg = Vt + (size_t)bh * HD * NSEQ;   // [64][2048]

    // staging geometry: 512 16B-chunks per 64x64 tile; thread covers chunks
    // tid + 128*k (rows r0+16k — same row&7 -> same source swizzle)
    const int r0 = tid >> 3;                       // 0..15
    const int cs = ((tid & 7) ^ (r0 & 7)) << 3;    // inverse-swizzled src col

    // Q fragments straight from global: wave wid owns q rows wid*32..+31
    bf16x8 aq[2][2];
#pragma unroll
    for (int g = 0; g < 2; ++g)
#pragma unroll
        for (int kk = 0; kk < 2; ++kk)
            aq[g][kk] = *(const bf16x8*)
                &Qg[(wid * 32 + g * 16 + l15) * HD + quad * 8 + 32 * kk];

    union { u16 s[8]; bf16x8 v; } oneu;
#pragma unroll
    for (int ii = 0; ii < 8; ++ii) oneu.s[ii] = 0x3f80;   // bf16 1.0
    const bf16x8 vone = oneu.v;

    f32x4 O[2][4];
#pragma unroll
    for (int g = 0; g < 2; ++g)
#pragma unroll
        for (int t = 0; t < 4; ++t) O[g][t] = (f32x4){0.f, 0.f, 0.f, 0.f};
    f32x4 lacc[2];
    lacc[0] = (f32x4){0.f, 0.f, 0.f, 0.f};
    lacc[1] = (f32x4){0.f, 0.f, 0.f, 0.f};

    STAGE_KV(0, 0);
    __syncthreads();

    for (int kt = 0; kt < NSEQ / 64; ++kt) {
        const int cur = kt & 1;
        if (kt + 1 < NSEQ / 64) STAGE_KV(cur ^ 1, kt + 1);

        // S^T = K . Q^T : D[key=mt*16+quad*4+r][qrow=l15], per q-group
        f32x4 sacc[2][4];
#pragma unroll
        for (int g = 0; g < 2; ++g)
#pragma unroll
            for (int mt = 0; mt < 4; ++mt)
                sacc[g][mt] = (f32x4){0.f, 0.f, 0.f, 0.f};
        __builtin_amdgcn_s_setprio(1);
#pragma unroll
        for (int kk = 0; kk < 2; ++kk) {
#pragma unroll
            for (int mt = 0; mt < 4; ++mt) {
                bf16x8 ak = *(const bf16x8*)
                    &Ks[cur][(mt * 16 + l15) * 64 + ((quad * 8 + 32 * kk) ^ swz)];
                sacc[0][mt] = __builtin_amdgcn_mfma_f32_16x16x32_bf16(
                    ak, aq[0][kk], sacc[0][mt], 0, 0, 0);
                sacc[1][mt] = __builtin_amdgcn_mfma_f32_16x16x32_bf16(
                    ak, aq[1][kk], sacc[1][mt], 0, 0, 0);
            }
        }
        __builtin_amdgcn_s_setprio(0);

        // fixed-max softmax, in-lane; P -> wave-private LDS (transpose)
#pragma unroll
        for (int g = 0; g < 2; ++g)
#pragma unroll
            for (int mt = 0; mt < 4; ++mt) {
                f32x4 ev;
#pragma unroll
                for (int r = 0; r < 4; ++r) ev[r] = __expf(sacc[g][mt][r]);
                bf16x4t pbk = __builtin_convertvector(ev, bf16x4t);
                *(bf16x4t*)&Ps[wid][g][l15 * 64 + ((mt * 16 + quad * 4) ^ swz)]
                    = pbk;
            }
        bf16x8 ap[2][2];
#pragma unroll
        for (int g = 0; g < 2; ++g)
#pragma unroll
            for (int kk = 0; kk < 2; ++kk)
                ap[g][kk] = *(const bf16x8*)
                    &Ps[wid][g][l15 * 64 + ((quad * 8 + 32 * kk) ^ swz)];

        // O += P . V ; denominator via ones-fragment MFMA
        __builtin_amdgcn_s_setprio(1);
#pragma unroll
        for (int kk = 0; kk < 2; ++kk) {
            lacc[0] = __builtin_amdgcn_mfma_f32_16x16x32_bf16(
                ap[0][kk], vone, lacc[0], 0, 0, 0);
            lacc[1] = __builtin_amdgcn_mfma_f32_16x16x32_bf16(
                ap[1][kk], vone, lacc[1], 0, 0, 0);
#pragma unroll
            for (int t = 0; t < 4; ++t) {
                bf16x8 bv = *(const bf16x8*)
                    &Vs[cur][(t * 16 + l15) * 64 + ((quad * 8 + 32 * kk) ^ swz)];
                O[0][t] = __builtin_amdgcn_mfma_f32_16x16x32_bf16(
                    ap[0][kk], bv, O[0][t], 0, 0, 0);
                O[1][t] = __builtin_amdgcn_mfma_f32_16x16x32_bf16(
                    ap[1][kk], bv, O[1][t], 0, 0, 0);
            }
        }
        __builtin_amdgcn_s_setprio(0);

        __syncthreads();   // drains staging loads; orders dbuf swap
    }

    // lacc[g][r] = sum_k P for qrow quad*4+r — same row layout as O[g][t][r]
    const int b = bh / NH, h = bh % NH;
#pragma unroll
    for (int g = 0; g < 2; ++g) {
        float inv4[4];
#pragma unroll
        for (int r = 0; r < 4; ++r) inv4[r] = 1.0f / lacc[g][r];
#pragma unroll
        for (int r = 0; r < 4; ++r) {
            size_t orow = (size_t)b * NSEQ + qt * 64 + wid * 32 + g * 16
                          + quad * 4 + r;
#pragma unroll
            for (int t = 0; t < 4; ++t)
                AO[orow * CDIM + h * HD + t * 16 + l15] =
                    f2bf(O[g][t][r] * inv4[r]);
        }
    }
}

// ---------------------------------------------------------------------------
// Kernel 3: out = AO @ Wproj^T + bias, bf16 MFMA (R1-proven version).
// 64x64 tiles, grid (64,12)=768 blocks (3/CU). A staged via global_load_lds
// with source-side XOR swizzle; W converted fp32->bf16 during staging.
// ---------------------------------------------------------------------------
__global__ __launch_bounds__(256)
void proj_kernel(const u16* __restrict__ A, const float* __restrict__ Wf,
                 const float* __restrict__ bias, float* __restrict__ out)
{
    __shared__ __align__(16) u16 As[64 * 64];
    __shared__ __align__(16) u16 Bs[64 * 64];
    const int tid  = threadIdx.x;
    const int lane = tid & 63;
    const int wid  = tid >> 6;
    const int l15  = lane & 15;
    const int quad = lane >> 4;
    const int swz  = (l15 & 7) << 3;
    const int wr = wid >> 1, wc = wid & 1;
    const int m0 = blockIdx.x * 64;
    const int n0 = blockIdx.y * 64;

    const int r0 = tid >> 3;                        // 0..31
    const int cs = ((tid & 7) ^ (r0 & 7)) << 3;     // swizzled A source col
    const int c8 = (tid & 7) << 3;
    const int bswz = c8 ^ ((r0 & 7) << 3);          // swizzled B dest col

    f32x4 acc[2][2];
#pragma unroll
    for (int mi = 0; mi < 2; ++mi)
#pragma unroll
        for (int ni = 0; ni < 2; ++ni)
            acc[mi][ni] = (f32x4){0.f, 0.f, 0.f, 0.f};

    for (int kt = 0; kt < CDIM; kt += 64) {
        __syncthreads();
        // A: 64x64 bf16 tile, async direct-to-LDS (chunks tid, tid+256)
        GLD16(A + ((size_t)(m0 + r0) * CDIM + kt + cs),      &As[wid * 512]);
        GLD16(A + ((size_t)(m0 + r0 + 32) * CDIM + kt + cs), &As[wid * 512 + 2048]);
        // B: 64x64 fp32 -> bf16, swizzled register-staged write
        {
            size_t gb0 = (size_t)(n0 + r0) * CDIM + kt + c8;
            size_t gb1 = (size_t)(n0 + r0 + 32) * CDIM + kt + c8;
            float4 w0 = *(const float4*)&Wf[gb0];
            float4 w1 = *(const float4*)&Wf[gb0 + 4];
            float4 w2 = *(const float4*)&Wf[gb1];
            float4 w3 = *(const float4*)&Wf[gb1 + 4];
            *(uint4*)&Bs[r0 * 64 + bswz]        = pack8(w0, w1);
            *(uint4*)&Bs[(r0 + 32) * 64 + bswz] = pack8(w2, w3);
        }
        __syncthreads();

#pragma unroll
        for (int k = 0; k < 2; ++k) {
            bf16x8 af[2], bf[2];
#pragma unroll
            for (int mi = 0; mi < 2; ++mi)
                af[mi] = *(const bf16x8*)
                    &As[(wr * 32 + mi * 16 + l15) * 64 + ((quad * 8 + 32 * k) ^ swz)];
#pragma unroll
            for (int ni = 0; ni < 2; ++ni)
                bf[ni] = *(const bf16x8*)
                    &Bs[(wc * 32 + ni * 16 + l15) * 64 + ((quad * 8 + 32 * k) ^ swz)];
#pragma unroll
            for (int mi = 0; mi < 2; ++mi)
#pragma unroll
                for (int ni = 0; ni < 2; ++ni)
                    acc[mi][ni] = __builtin_amdgcn_mfma_f32_16x16x32_bf16(
                        af[mi], bf[ni], acc[mi][ni], 0, 0, 0);
        }
    }

#pragma unroll
    for (int ni = 0; ni < 2; ++ni) {
        int col = n0 + wc * 32 + ni * 16 + l15;
        float bb = bias[col];
#pragma unroll
        for (int mi = 0; mi < 2; ++mi) {
            int rw = m0 + wr * 32 + mi * 16 + quad * 4;
#pragma unroll
            for (int r = 0; r < 4; ++r)
                out[(size_t)(rw + r) * CDIM + col] = acc[mi][ni][r] + bb;
        }
    }
}

// ---------------------------------------------------------------------------
extern "C" void kernel_launch(void* const* d_in, const int* in_sizes, int n_in,
                              void* d_out, int out_size, void* d_ws,
                              size_t ws_size, hipStream_t stream)
{
    const float* X     = (const float*)d_in[0];   // [2, 2048, 768]
    const float* Wqkv  = (const float*)d_in[1];   // [2304, 768]
    const float* Wproj = (const float*)d_in[2];   // [768, 768]
    const float* bias  = (const float*)d_in[3];   // [768]
    float* out = (float*)d_out;                   // [2, 2048, 768]

    const size_t per_buf = (size_t)NB * NH * NSEQ * HD;   // 3145728
    u16* Qb  = (u16*)d_ws;
    u16* Kb  = Qb + per_buf;
    u16* Vb  = Kb + per_buf;                      // [B,H,64,N]
    u16* AOb = Vb + per_buf;                      // [4096, 768] bf16

    qkv_mfma_kernel<<<dim3(32, 18), 256, 0, stream>>>(X, Wqkv, Qb, Kb, Vb);
    attn_kernel<<<dim3(768), 128, 0, stream>>>(Qb, Kb, Vb, AOb);
    proj_kernel<<<dim3(64, 12), 256, 0, stream>>>(AOb, Wproj, bias, out);
}

// Round 4
// 162.168 us; speedup vs baseline: 1.8169x; 1.0619x over previous
//
#include <hip/hip_runtime.h>
#include <math.h>

#define NSEQ 2048
#define CDIM 768
#define NH   12
#define HD   64
#define NB   2

typedef unsigned short u16;
typedef __attribute__((ext_vector_type(8))) short bf16x8;   // 8 bf16 = 4 VGPRs
typedef __attribute__((ext_vector_type(4))) float f32x4;
typedef __attribute__((ext_vector_type(8))) float f32x8;
typedef __attribute__((ext_vector_type(4))) __bf16 bf16x4t;
typedef __attribute__((ext_vector_type(8))) __bf16 bf16x8t;

// fp32 -> bf16 round-to-nearest-even (scalar epilogue paths)
__device__ __forceinline__ u16 f2bf(float x) {
    unsigned int u = __float_as_uint(x);
    u += 0x7fffu + ((u >> 16) & 1u);
    return (u16)(u >> 16);
}

// pack 8 fp32 -> 8 bf16 via compiler-generated v_cvt_pk_bf16_f32
__device__ __forceinline__ uint4 pack8(float4 a, float4 b) {
    f32x8 v = {a.x, a.y, a.z, a.w, b.x, b.y, b.z, b.w};
    union { bf16x8t t; uint4 u; } o;
    o.t = __builtin_convertvector(v, bf16x8t);
    return o.u;
}

#define LSTR 72    // LDS row stride (u16): +8 pad
#define ESTR 136   // V-epilogue transpose tile stride (u16): 128+8

// async global->LDS, 16B per lane, LDS dest = wave-uniform base + lane*16
#define GLD16(gp, lp) __builtin_amdgcn_global_load_lds( \
    (__attribute__((address_space(1))) void*)(const void*)(gp), \
    (__attribute__((address_space(3))) void*)(void*)(lp), 16, 0, 0)

// ---------------------------------------------------------------------------
// Kernel 1: qkv = X @ Wqkv^T, bf16 MFMA, fp32 inputs converted in-register
// during staging. R12: retiled 128x128 -> 128(M)x64(N): grid 576 -> 1152
// blocks (was 2.25/CU grid-starved with every pipe <15% busy). 4 waves,
// each owns 32 tokens x the block's single head-column -> sel/h are
// BLOCK-uniform; V epilogue becomes one shared 64x128 transpose tile with
// full-256B-line stores. LDS 27.6KB (5 blocks/CU capacity). m-major-
// within-XCD bijective swizzle: co-resident blocks on an XCD share a
// 1.57MB X-slice (L2-resident) while sweeping W bands.
// Q,K: [B,H,N,64]; V: [B,H,64,N]. Fused scale (q), RoPE (q,k).
// ---------------------------------------------------------------------------
__global__ __launch_bounds__(256)
void qkv_mfma_kernel(const float* __restrict__ Xf, const float* __restrict__ Wf,
                     u16* __restrict__ Qb, u16* __restrict__ Kb,
                     u16* __restrict__ Vb)
{
    __shared__ __align__(16) u16 S[(128 + 64) * LSTR];   // 27648 B
    u16* As = S;                 // [128][72]
    u16* Bs = S + 128 * LSTR;    // [64][72]

    const int tid  = threadIdx.x;
    const int lane = tid & 63;
    const int wid  = tid >> 6;
    const int l15  = lane & 15;
    const int quad = lane >> 4;

    // XCD swizzle (bijective, 1152 = 8*144): XCD j owns L in [144j,144j+144),
    // enumerated m-major (m_tile = L/36) so co-resident blocks share X rows.
    const int f  = blockIdx.x;
    const int L  = (f & 7) * 144 + (f >> 3);
    const int m0 = (L / 36) * 128;     // token tile (0..31)
    const int n0 = (L % 36) * 64;      // head-column tile (0..35)

    const int row = tid >> 3, c8s = (tid & 7) << 3;   // 8-u16 chunk coords

    f32x4 acc[2][4];
#pragma unroll
    for (int mi = 0; mi < 2; ++mi)
#pragma unroll
        for (int ni = 0; ni < 4; ++ni)
            acc[mi][ni] = (f32x4){0.f, 0.f, 0.f, 0.f};

    float4 pa[4][2], pb[2][2];
#pragma unroll
    for (int it = 0; it < 4; ++it) {
        size_t ga = (size_t)(m0 + row + 32 * it) * CDIM + c8s;
        pa[it][0] = *(const float4*)&Xf[ga];
        pa[it][1] = *(const float4*)&Xf[ga + 4];
    }
#pragma unroll
    for (int it = 0; it < 2; ++it) {
        size_t gb = (size_t)(n0 + row + 32 * it) * CDIM + c8s;
        pb[it][0] = *(const float4*)&Wf[gb];
        pb[it][1] = *(const float4*)&Wf[gb + 4];
    }

    for (int kt = 0; kt < CDIM; kt += 64) {
        __syncthreads();
#pragma unroll
        for (int it = 0; it < 4; ++it)
            *(uint4*)&As[(row + 32 * it) * LSTR + c8s] =
                pack8(pa[it][0], pa[it][1]);
#pragma unroll
        for (int it = 0; it < 2; ++it)
            *(uint4*)&Bs[(row + 32 * it) * LSTR + c8s] =
                pack8(pb[it][0], pb[it][1]);
        __syncthreads();

        if (kt + 64 < CDIM) {
#pragma unroll
            for (int it = 0; it < 4; ++it) {
                size_t ga = (size_t)(m0 + row + 32 * it) * CDIM + kt + 64 + c8s;
                pa[it][0] = *(const float4*)&Xf[ga];
                pa[it][1] = *(const float4*)&Xf[ga + 4];
            }
#pragma unroll
            for (int it = 0; it < 2; ++it) {
                size_t gb = (size_t)(n0 + row + 32 * it) * CDIM + kt + 64 + c8s;
                pb[it][0] = *(const float4*)&Wf[gb];
                pb[it][1] = *(const float4*)&Wf[gb + 4];
            }
        }

#pragma unroll
        for (int k = 0; k < 2; ++k) {
            bf16x8 af[2];
#pragma unroll
            for (int mi = 0; mi < 2; ++mi)
                af[mi] = *(const bf16x8*)
                    &As[(wid * 32 + mi * 16 + l15) * LSTR + quad * 8 + 32 * k];
#pragma unroll
            for (int ni = 0; ni < 4; ++ni) {
                bf16x8 bfr = *(const bf16x8*)
                    &Bs[(ni * 16 + l15) * LSTR + quad * 8 + 32 * k];
#pragma unroll
                for (int mi = 0; mi < 2; ++mi)
                    acc[mi][ni] = __builtin_amdgcn_mfma_f32_16x16x32_bf16(
                        af[mi], bfr, acc[mi][ni], 0, 0, 0);
            }
        }
    }

    __syncthreads();   // all waves done reading As/Bs before overlay

    // C-layout: token row = wid*32 + mi*16 + quad*4 + r, feature col
    // (within head) = ni*16 + l15. Block's 64 cols = exactly one head.
    const int bi      = m0 >> 11;
    const int tokbase = m0 & 2047;
    const int nbase   = tokbase + wid * 32;
    const int sel     = n0 / CDIM;           // 0=q,1=k,2=v (block-uniform)
    const int h       = (n0 % CDIM) >> 6;

    if (sel == 2) {
        // shared 64(d) x 128(token) transpose tile
        u16* Ew = S;
#pragma unroll
        for (int ni = 0; ni < 4; ++ni)
#pragma unroll
            for (int mi = 0; mi < 2; ++mi)
#pragma unroll
                for (int r = 0; r < 4; ++r)
                    Ew[(ni * 16 + l15) * ESTR + wid * 32 + mi * 16 + quad * 4 + r]
                        = f2bf(acc[mi][ni][r]);
        __syncthreads();
        u16* dst = Vb + (size_t)(bi * NH + h) * HD * NSEQ;   // [64][2048]
#pragma unroll
        for (int it = 0; it < 4; ++it) {
            int idx = tid + 256 * it;          // 1024 chunks = 64 rows x 16
            int dd  = idx >> 4;
            int c8  = (idx & 15) << 3;
            *(uint4*)&dst[(size_t)dd * NSEQ + tokbase + c8] =
                *(const uint4*)&Ew[dd * ESTR + c8];
        }
    } else {
        u16* dst = ((sel == 0) ? Qb : Kb) + (size_t)(bi * NH + h) * NSEQ * HD;
        const float scl = (sel == 0) ? 0.125f : 1.0f;
        u16* Ew = S + wid * 32 * LSTR;         // wave-private 32x72 tile
#pragma unroll
        for (int ni = 0; ni < 4; ++ni) {
            int dd = ni * 16 + l15;
            float invf = expf(-0.14391156831212787f * (float)(dd & ~1));
#pragma unroll
            for (int mi = 0; mi < 2; ++mi) {
                f32x4 val = acc[mi][ni];
#pragma unroll
                for (int r = 0; r < 4; ++r) {
                    float e = val[r] * scl;
                    float p = __shfl_xor(e, 1);    // pair partner (col^1)
                    int n = nbase + mi * 16 + quad * 4 + r;
                    float sv, cv;
                    __sincosf((float)n * invf, &sv, &cv);
                    float o = (dd & 1) ? (e * cv + p * sv)
                                       : (e * cv - p * sv);
                    Ew[(mi * 16 + quad * 4 + r) * LSTR + dd] = f2bf(o);
                }
            }
        }
        // wave-private copy-out: 32 rows x 8 chunks = 256, 4 per lane
#pragma unroll
        for (int it = 0; it < 4; ++it) {
            int ch  = lane + 64 * it;
            int tr  = ch >> 3;
            int gc8 = (ch & 7) << 3;
            *(uint4*)&dst[(size_t)(nbase + tr) * HD + gc8] =
                *(const uint4*)&Ew[tr * LSTR + gc8];
        }
    }
}

// ---------------------------------------------------------------------------
// Kernel 2: flash attention, bf16 MFMA (exact R1 revert — proven 49.2 us).
// S^T orientation, fixed-max softmax; gload_lds K/V staging with source-side
// XOR swizzle; K/V double-buffer + ONE barrier/iter; ones-MFMA denominator;
// XCD bh-pinning; 4 waves x 16 q-rows (TLP > per-wave efficiency: R3's
// 2-wave variant with 2x LDS amortization lost 23% on wave count alone).
// ---------------------------------------------------------------------------
#define STAGE_KV(BUF, kt_) do {                                               \
    GLD16(Kg + ((size_t)(((kt_) << 6) + r0) * HD + cs),                       \
          &Ks[BUF][wid * 512]);                                               \
    GLD16(Kg + ((size_t)(((kt_) << 6) + r0 + 32) * HD + cs),                  \
          &Ks[BUF][wid * 512 + 2048]);                                        \
    GLD16(Vg + ((size_t)r0 * NSEQ + ((kt_) << 6) + cs),                       \
          &Vs[BUF][wid * 512]);                                               \
    GLD16(Vg + ((size_t)(r0 + 32) * NSEQ + ((kt_) << 6) + cs),                \
          &Vs[BUF][wid * 512 + 2048]);                                        \
} while (0)

#define ATTN_STEP(kt_, CUR, NXT) do {                                         \
    if ((kt_) + 1 < NSEQ / 64) STAGE_KV(NXT, (kt_) + 1);                      \
    f32x4 sacc[4];                                                            \
    _Pragma("unroll")                                                         \
    for (int mt = 0; mt < 4; ++mt) sacc[mt] = (f32x4){0.f, 0.f, 0.f, 0.f};    \
    _Pragma("unroll")                                                         \
    for (int k = 0; k < 2; ++k) {                                             \
        _Pragma("unroll")                                                     \
        for (int mt = 0; mt < 4; ++mt) {                                      \
            bf16x8 ak = *(const bf16x8*)                                      \
                &Ks[CUR][(mt * 16 + l15) * 64 + ((quad * 8 + 32 * k) ^ swz)]; \
            sacc[mt] = __builtin_amdgcn_mfma_f32_16x16x32_bf16(               \
                ak, aq[k], sacc[mt], 0, 0, 0);                                \
        }                                                                     \
    }                                                                         \
    _Pragma("unroll")                                                         \
    for (int mt = 0; mt < 4; ++mt) {                                          \
        f32x4 ev;                                                             \
        _Pragma("unroll")                                                     \
        for (int r = 0; r < 4; ++r) ev[r] = __expf(sacc[mt][r]);              \
        bf16x4t pbk = __builtin_convertvector(ev, bf16x4t);                   \
        *(bf16x4t*)&Pw[l15 * 64 + ((mt * 16 + quad * 4) ^ swz)] = pbk;        \
    }                                                                         \
    _Pragma("unroll")                                                         \
    for (int k = 0; k < 2; ++k) {                                             \
        bf16x8 ap = *(const bf16x8*)                                          \
            &Pw[l15 * 64 + ((quad * 8 + 32 * k) ^ swz)];                      \
        lacc = __builtin_amdgcn_mfma_f32_16x16x32_bf16(                       \
            ap, vone, lacc, 0, 0, 0);                                         \
        _Pragma("unroll")                                                     \
        for (int t = 0; t < 4; ++t) {                                         \
            bf16x8 bv = *(const bf16x8*)                                      \
                &Vs[CUR][(t * 16 + l15) * 64 + ((quad * 8 + 32 * k) ^ swz)];  \
            O[t] = __builtin_amdgcn_mfma_f32_16x16x32_bf16(                   \
                ap, bv, O[t], 0, 0, 0);                                       \
        }                                                                     \
    }                                                                         \
    __syncthreads();                                                          \
} while (0)

__global__ __launch_bounds__(256)
void attn_kernel(const u16* __restrict__ Qb, const u16* __restrict__ Kb,
                 const u16* __restrict__ Vt, u16* __restrict__ AO)
{
    __shared__ __align__(16) u16 Ks[2][64 * 64];
    __shared__ __align__(16) u16 Vs[2][64 * 64];
    __shared__ __align__(16) u16 Ps[4][16 * 64];   // wave-private P tiles

    const int tid  = threadIdx.x;
    const int lane = tid & 63;
    const int wid  = tid >> 6;
    const int l15  = lane & 15;
    const int quad = lane >> 4;
    const int swz  = (l15 & 7) << 3;   // XOR swizzle for frag reads/P ops

    // XCD swizzle: xcd = f&7 -> bh in {3*xcd .. 3*xcd+2}; 96 blocks/XCD.
    const int f  = blockIdx.x;
    const int i  = f >> 3;
    const int bh = (f & 7) * 3 + (i >> 5);   // 0..23
    const int qt = i & 31;                   // 0..31

    const u16* Qg = Qb + ((size_t)bh * NSEQ + qt * 64) * HD;
    const u16* Kg = Kb + (size_t)bh * NSEQ * HD;
    const u16* Vg = Vt + (size_t)bh * HD * NSEQ;   // [64][2048]

    // staging geometry: 512 16B-chunks per 64x64 tile; thread covers chunks
    // tid and tid+256 (rows r0, r0+32 — same row&7, so same source swizzle)
    const int r0 = tid >> 3;
    const int cs = ((tid & 7) ^ (r0 & 7)) << 3;    // inverse-swizzled src col

    // Q fragments straight from global (rows are 128B; one-time read)
    bf16x8 aq[2];
    aq[0] = *(const bf16x8*)&Qg[(wid * 16 + l15) * HD + quad * 8];
    aq[1] = *(const bf16x8*)&Qg[(wid * 16 + l15) * HD + quad * 8 + 32];

    union { u16 s[8]; bf16x8 v; } oneu;
#pragma unroll
    for (int ii = 0; ii < 8; ++ii) oneu.s[ii] = 0x3f80;   // bf16 1.0
    const bf16x8 vone = oneu.v;

    f32x4 O[4];
#pragma unroll
    for (int t = 0; t < 4; ++t) O[t] = (f32x4){0.f, 0.f, 0.f, 0.f};
    f32x4 lacc = (f32x4){0.f, 0.f, 0.f, 0.f};   // softmax denominator rows

    u16* Pw = Ps[wid];

    STAGE_KV(0, 0);
    __syncthreads();

    for (int kt = 0; kt < NSEQ / 64; kt += 2) {
        ATTN_STEP(kt, 0, 1);
        ATTN_STEP(kt + 1, 1, 0);
    }

    // lacc[r] = sum_k P for qrow quad*4+r — same row layout as O[t][r]
    float inv4[4];
#pragma unroll
    for (int r = 0; r < 4; ++r) inv4[r] = 1.0f / lacc[r];

    const int b = bh / NH, h = bh % NH;
#pragma unroll
    for (int r = 0; r < 4; ++r) {
        size_t orow = (size_t)b * NSEQ + qt * 64 + wid * 16 + quad * 4 + r;
#pragma unroll
        for (int t = 0; t < 4; ++t)
            AO[orow * CDIM + h * HD + t * 16 + l15] = f2bf(O[t][r] * inv4[r]);
    }
}

// ---------------------------------------------------------------------------
// Kernel 3: out = AO @ Wproj^T + bias, bf16 MFMA (R1-proven version).
// 64x64 tiles, grid (64,12)=768 blocks (3/CU). A staged via global_load_lds
// with source-side XOR swizzle; W converted fp32->bf16 during staging.
// ---------------------------------------------------------------------------
__global__ __launch_bounds__(256)
void proj_kernel(const u16* __restrict__ A, const float* __restrict__ Wf,
                 const float* __restrict__ bias, float* __restrict__ out)
{
    __shared__ __align__(16) u16 As[64 * 64];
    __shared__ __align__(16) u16 Bs[64 * 64];
    const int tid  = threadIdx.x;
    const int lane = tid & 63;
    const int wid  = tid >> 6;
    const int l15  = lane & 15;
    const int quad = lane >> 4;
    const int swz  = (l15 & 7) << 3;
    const int wr = wid >> 1, wc = wid & 1;
    const int m0 = blockIdx.x * 64;
    const int n0 = blockIdx.y * 64;

    const int r0 = tid >> 3;                        // 0..31
    const int cs = ((tid & 7) ^ (r0 & 7)) << 3;     // swizzled A source col
    const int c8 = (tid & 7) << 3;
    const int bswz = c8 ^ ((r0 & 7) << 3);          // swizzled B dest col

    f32x4 acc[2][2];
#pragma unroll
    for (int mi = 0; mi < 2; ++mi)
#pragma unroll
        for (int ni = 0; ni < 2; ++ni)
            acc[mi][ni] = (f32x4){0.f, 0.f, 0.f, 0.f};

    for (int kt = 0; kt < CDIM; kt += 64) {
        __syncthreads();
        // A: 64x64 bf16 tile, async direct-to-LDS (chunks tid, tid+256)
        GLD16(A + ((size_t)(m0 + r0) * CDIM + kt + cs),      &As[wid * 512]);
        GLD16(A + ((size_t)(m0 + r0 + 32) * CDIM + kt + cs), &As[wid * 512 + 2048]);
        // B: 64x64 fp32 -> bf16, swizzled register-staged write
        {
            size_t gb0 = (size_t)(n0 + r0) * CDIM + kt + c8;
            size_t gb1 = (size_t)(n0 + r0 + 32) * CDIM + kt + c8;
            float4 w0 = *(const float4*)&Wf[gb0];
            float4 w1 = *(const float4*)&Wf[gb0 + 4];
            float4 w2 = *(const float4*)&Wf[gb1];
            float4 w3 = *(const float4*)&Wf[gb1 + 4];
            *(uint4*)&Bs[r0 * 64 + bswz]        = pack8(w0, w1);
            *(uint4*)&Bs[(r0 + 32) * 64 + bswz] = pack8(w2, w3);
        }
        __syncthreads();

#pragma unroll
        for (int k = 0; k < 2; ++k) {
            bf16x8 af[2], bf[2];
#pragma unroll
            for (int mi = 0; mi < 2; ++mi)
                af[mi] = *(const bf16x8*)
                    &As[(wr * 32 + mi * 16 + l15) * 64 + ((quad * 8 + 32 * k) ^ swz)];
#pragma unroll
            for (int ni = 0; ni < 2; ++ni)
                bf[ni] = *(const bf16x8*)
                    &Bs[(wc * 32 + ni * 16 + l15) * 64 + ((quad * 8 + 32 * k) ^ swz)];
#pragma unroll
            for (int mi = 0; mi < 2; ++mi)
#pragma unroll
                for (int ni = 0; ni < 2; ++ni)
                    acc[mi][ni] = __builtin_amdgcn_mfma_f32_16x16x32_bf16(
                        af[mi], bf[ni], acc[mi][ni], 0, 0, 0);
        }
    }

#pragma unroll
    for (int ni = 0; ni < 2; ++ni) {
        int col = n0 + wc * 32 + ni * 16 + l15;
        float bb = bias[col];
#pragma unroll
        for (int mi = 0; mi < 2; ++mi) {
            int rw = m0 + wr * 32 + mi * 16 + quad * 4;
#pragma unroll
            for (int r = 0; r < 4; ++r)
                out[(size_t)(rw + r) * CDIM + col] = acc[mi][ni][r] + bb;
        }
    }
}

// ---------------------------------------------------------------------------
extern "C" void kernel_launch(void* const* d_in, const int* in_sizes, int n_in,
                              void* d_out, int out_size, void* d_ws,
                              size_t ws_size, hipStream_t stream)
{
    const float* X     = (const float*)d_in[0];   // [2, 2048, 768]
    const float* Wqkv  = (const float*)d_in[1];   // [2304, 768]
    const float* Wproj = (const float*)d_in[2];   // [768, 768]
    const float* bias  = (const float*)d_in[3];   // [768]
    float* out = (float*)d_out;                   // [2, 2048, 768]

    const size_t per_buf = (size_t)NB * NH * NSEQ * HD;   // 3145728
    u16* Qb  = (u16*)d_ws;
    u16* Kb  = Qb + per_buf;
    u16* Vb  = Kb + per_buf;                      // [B,H,64,N]
    u16* AOb = Vb + per_buf;                      // [4096, 768] bf16

    qkv_mfma_kernel<<<dim3(1152), 256, 0, stream>>>(X, Wqkv, Qb, Kb, Vb);
    attn_kernel<<<dim3(768), 256, 0, stream>>>(Qb, Kb, Vb, AOb);
    proj_kernel<<<dim3(64, 12), 256, 0, stream>>>(AOb, Wproj, bias, out);
}

// Round 5
// 147.820 us; speedup vs baseline: 1.9933x; 1.0971x over previous
//
#include <hip/hip_runtime.h>
#include <math.h>

#define NSEQ 2048
#define CDIM 768
#define NH   12
#define HD   64
#define NB   2

typedef unsigned short u16;
typedef __attribute__((ext_vector_type(8))) short bf16x8;   // 8 bf16 = 4 VGPRs
typedef __attribute__((ext_vector_type(4))) float f32x4;
typedef __attribute__((ext_vector_type(8))) float f32x8;
typedef __attribute__((ext_vector_type(4))) __bf16 bf16x4t;
typedef __attribute__((ext_vector_type(8))) __bf16 bf16x8t;

// fp32 -> bf16 round-to-nearest-even (scalar epilogue paths)
__device__ __forceinline__ u16 f2bf(float x) {
    unsigned int u = __float_as_uint(x);
    u += 0x7fffu + ((u >> 16) & 1u);
    return (u16)(u >> 16);
}

// pack 8 fp32 -> 8 bf16 via compiler-generated v_cvt_pk_bf16_f32
__device__ __forceinline__ uint4 pack8(float4 a, float4 b) {
    f32x8 v = {a.x, a.y, a.z, a.w, b.x, b.y, b.z, b.w};
    union { bf16x8t t; uint4 u; } o;
    o.t = __builtin_convertvector(v, bf16x8t);
    return o.u;
}

#define LSTR 72    // epilogue scratch stride (u16)
#define ESTR 136   // V-epilogue transpose tile stride (u16): 128+8

// async global->LDS, 16B per lane, LDS dest = wave-uniform base + lane*16
#define GLD16(gp, lp) __builtin_amdgcn_global_load_lds( \
    (__attribute__((address_space(1))) void*)(const void*)(gp), \
    (__attribute__((address_space(3))) void*)(void*)(lp), 16, 0, 0)

// ---------------------------------------------------------------------------
// Kernel 0 (R13): one-shot fp32->bf16 conversion of X, Wqkv, Wproj.
// Rationale: R4 counters showed qkv invariant at ~52us across occupancy
// 13->23% with 680MB of fp32 L2/L3 amplified traffic (X re-read 36x, W 32x).
// Bytes are the lever: halve every cache-level transfer and enable
// global_load_lds staging in qkv/proj. Q-scale 0.125 baked into Wq rows.
// 688128 chunks of 8 floats, exactly 2688x256 threads, no bounds check.
// ---------------------------------------------------------------------------
__global__ __launch_bounds__(256)
void conv_kernel(const float* __restrict__ Xf, const float* __restrict__ Wqkv,
                 const float* __restrict__ Wproj, u16* __restrict__ Xb,
                 u16* __restrict__ Wqb, u16* __restrict__ Wpb)
{
    const int c = blockIdx.x * 256 + threadIdx.x;   // 0..688127
    const float* src; u16* dst; int lc; float scl = 1.0f;
    if (c < 393216)      { src = Xf;    dst = Xb;  lc = c; }
    else if (c < 614400) { src = Wqkv;  dst = Wqb; lc = c - 393216;
                           if (lc < 73728) scl = 0.125f; }   // Wq rows
    else                 { src = Wproj; dst = Wpb; lc = c - 614400; }
    float4 a = *(const float4*)&src[(size_t)lc * 8];
    float4 b = *(const float4*)&src[(size_t)lc * 8 + 4];
    a.x *= scl; a.y *= scl; a.z *= scl; a.w *= scl;
    b.x *= scl; b.y *= scl; b.z *= scl; b.w *= scl;
    *(uint4*)&dst[(size_t)lc * 8] = pack8(a, b);
}

// ---------------------------------------------------------------------------
// Kernel 1: qkv = Xb @ Wqkvb^T, pure bf16 MFMA. R13: both operands staged
// via global_load_lds (linear LDS + source-side XOR swizzle, rule 21),
// double-buffered, ONE barrier per K-step (attn-proven structure). Tile
// 128(M)x64(N), 4 waves each own 32 tokens x the block's single head-col.
// n-major-within-XCD bijective swizzle: per-XCD live set = 4 X-slices
// (786KB bf16) + ~24 W-panels (2.4MB) < 4MB L2. LDS 48KB -> 3 blocks/CU.
// Q,K: [B,H,N,64]; V: [B,H,64,N]. RoPE fused (scale pre-baked in Wq).
// ---------------------------------------------------------------------------
#define QKV_STAGE(BUF, kt_) do {                                              \
    _Pragma("unroll")                                                         \
    for (int it = 0; it < 4; ++it) {                                          \
        int ch = tid + 256 * it; int rr = ch >> 3;                            \
        int sc = ((ch & 7) ^ (rr & 7)) << 3;                                  \
        GLD16(Xg + (size_t)(m0 + rr) * CDIM + (kt_) + sc, &S[BUF][ch * 8]);   \
    }                                                                         \
    _Pragma("unroll")                                                         \
    for (int it = 0; it < 2; ++it) {                                          \
        int ch = tid + 256 * it; int rr = ch >> 3;                            \
        int sc = ((ch & 7) ^ (rr & 7)) << 3;                                  \
        GLD16(Wg + (size_t)(n0 + rr) * CDIM + (kt_) + sc,                     \
              &S[BUF][8192 + ch * 8]);                                        \
    }                                                                         \
} while (0)

__global__ __launch_bounds__(256)
void qkv_mfma_kernel(const u16* __restrict__ Xg, const u16* __restrict__ Wg,
                     u16* __restrict__ Qb, u16* __restrict__ Kb,
                     u16* __restrict__ Vb)
{
    __shared__ __align__(16) u16 S[2][12288];   // [buf][A 128x64 | B 64x64]

    const int tid  = threadIdx.x;
    const int lane = tid & 63;
    const int wid  = tid >> 6;
    const int l15  = lane & 15;
    const int quad = lane >> 4;
    const int swz  = (l15 & 7) << 3;

    // n-major-within-XCD bijective swizzle (1152 = 8 XCD x 4 m x 36 n)
    const int f  = blockIdx.x;
    const int xc = f & 7;
    const int s  = f >> 3;                  // 0..143
    const int m0 = (xc * 4 + (s & 3)) * 128;
    const int n0 = (s >> 2) * 64;

    f32x4 acc[2][4];
#pragma unroll
    for (int mi = 0; mi < 2; ++mi)
#pragma unroll
        for (int ni = 0; ni < 4; ++ni)
            acc[mi][ni] = (f32x4){0.f, 0.f, 0.f, 0.f};

    QKV_STAGE(0, 0);
    __syncthreads();

    int cur = 0;
    for (int kt = 0; kt < CDIM; kt += 64) {
        if (kt + 64 < CDIM) QKV_STAGE(cur ^ 1, kt + 64);

#pragma unroll
        for (int k = 0; k < 2; ++k) {
            bf16x8 af[2];
#pragma unroll
            for (int mi = 0; mi < 2; ++mi)
                af[mi] = *(const bf16x8*)
                    &S[cur][(wid * 32 + mi * 16 + l15) * 64
                            + ((quad * 8 + 32 * k) ^ swz)];
#pragma unroll
            for (int ni = 0; ni < 4; ++ni) {
                bf16x8 bfr = *(const bf16x8*)
                    &S[cur][8192 + (ni * 16 + l15) * 64
                            + ((quad * 8 + 32 * k) ^ swz)];
#pragma unroll
                for (int mi = 0; mi < 2; ++mi)
                    acc[mi][ni] = __builtin_amdgcn_mfma_f32_16x16x32_bf16(
                        af[mi], bfr, acc[mi][ni], 0, 0, 0);
            }
        }
        __syncthreads();
        cur ^= 1;
    }

    // Epilogue. token row = wid*32 + mi*16 + quad*4 + r; col = ni*16 + l15.
    // Block's 64 cols = exactly one head; sel/h block-uniform.
    const int bi      = m0 >> 11;
    const int tokbase = m0 & 2047;
    const int nbase   = tokbase + wid * 32;
    const int sel     = n0 / CDIM;           // 0=q,1=k,2=v
    const int h       = (n0 % CDIM) >> 6;
    u16* Sf = &S[0][0];

    if (sel == 2) {
        u16* Ew = Sf;                        // shared 64(d) x 128(tok) tile
#pragma unroll
        for (int ni = 0; ni < 4; ++ni)
#pragma unroll
            for (int mi = 0; mi < 2; ++mi)
#pragma unroll
                for (int r = 0; r < 4; ++r)
                    Ew[(ni * 16 + l15) * ESTR + wid * 32 + mi * 16 + quad * 4 + r]
                        = f2bf(acc[mi][ni][r]);
        __syncthreads();
        u16* dst = Vb + (size_t)(bi * NH + h) * HD * NSEQ;   // [64][2048]
#pragma unroll
        for (int it = 0; it < 4; ++it) {
            int idx = tid + 256 * it;          // 1024 chunks = 64 rows x 16
            int dd  = idx >> 4;
            int c8  = (idx & 15) << 3;
            *(uint4*)&dst[(size_t)dd * NSEQ + tokbase + c8] =
                *(const uint4*)&Ew[dd * ESTR + c8];
        }
    } else {
        u16* dst = ((sel == 0) ? Qb : Kb) + (size_t)(bi * NH + h) * NSEQ * HD;
        u16* Ew = Sf + wid * 32 * LSTR;        // wave-private 32x72 tile
#pragma unroll
        for (int ni = 0; ni < 4; ++ni) {
            int dd = ni * 16 + l15;
            float invf = expf(-0.14391156831212787f * (float)(dd & ~1));
#pragma unroll
            for (int mi = 0; mi < 2; ++mi) {
                f32x4 val = acc[mi][ni];
#pragma unroll
                for (int r = 0; r < 4; ++r) {
                    float e = val[r];
                    float p = __shfl_xor(e, 1);    // pair partner (col^1)
                    int n = nbase + mi * 16 + quad * 4 + r;
                    float sv, cv;
                    __sincosf((float)n * invf, &sv, &cv);
                    float o = (dd & 1) ? (e * cv + p * sv)
                                       : (e * cv - p * sv);
                    Ew[(mi * 16 + quad * 4 + r) * LSTR + dd] = f2bf(o);
                }
            }
        }
#pragma unroll
        for (int it = 0; it < 4; ++it) {
            int ch  = lane + 64 * it;          // 32 rows x 8 chunks
            int tr  = ch >> 3;
            int gc8 = (ch & 7) << 3;
            *(uint4*)&dst[(size_t)(nbase + tr) * HD + gc8] =
                *(const uint4*)&Ew[tr * LSTR + gc8];
        }
    }
}

// ---------------------------------------------------------------------------
// Kernel 2: flash attention, bf16 MFMA (unchanged — proven 49.5 us).
// ---------------------------------------------------------------------------
#define STAGE_KV(BUF, kt_) do {                                               \
    GLD16(Kg + ((size_t)(((kt_) << 6) + r0) * HD + cs),                       \
          &Ks[BUF][wid * 512]);                                               \
    GLD16(Kg + ((size_t)(((kt_) << 6) + r0 + 32) * HD + cs),                  \
          &Ks[BUF][wid * 512 + 2048]);                                        \
    GLD16(Vg + ((size_t)r0 * NSEQ + ((kt_) << 6) + cs),                       \
          &Vs[BUF][wid * 512]);                                               \
    GLD16(Vg + ((size_t)(r0 + 32) * NSEQ + ((kt_) << 6) + cs),                \
          &Vs[BUF][wid * 512 + 2048]);                                        \
} while (0)

#define ATTN_STEP(kt_, CUR, NXT) do {                                         \
    if ((kt_) + 1 < NSEQ / 64) STAGE_KV(NXT, (kt_) + 1);                      \
    f32x4 sacc[4];                                                            \
    _Pragma("unroll")                                                         \
    for (int mt = 0; mt < 4; ++mt) sacc[mt] = (f32x4){0.f, 0.f, 0.f, 0.f};    \
    _Pragma("unroll")                                                         \
    for (int k = 0; k < 2; ++k) {                                             \
        _Pragma("unroll")                                                     \
        for (int mt = 0; mt < 4; ++mt) {                                      \
            bf16x8 ak = *(const bf16x8*)                                      \
                &Ks[CUR][(mt * 16 + l15) * 64 + ((quad * 8 + 32 * k) ^ swz)]; \
            sacc[mt] = __builtin_amdgcn_mfma_f32_16x16x32_bf16(               \
                ak, aq[k], sacc[mt], 0, 0, 0);                                \
        }                                                                     \
    }                                                                         \
    _Pragma("unroll")                                                         \
    for (int mt = 0; mt < 4; ++mt) {                                          \
        f32x4 ev;                                                             \
        _Pragma("unroll")                                                     \
        for (int r = 0; r < 4; ++r) ev[r] = __expf(sacc[mt][r]);              \
        bf16x4t pbk = __builtin_convertvector(ev, bf16x4t);                   \
        *(bf16x4t*)&Pw[l15 * 64 + ((mt * 16 + quad * 4) ^ swz)] = pbk;        \
    }                                                                         \
    _Pragma("unroll")                                                         \
    for (int k = 0; k < 2; ++k) {                                             \
        bf16x8 ap = *(const bf16x8*)                                          \
            &Pw[l15 * 64 + ((quad * 8 + 32 * k) ^ swz)];                      \
        lacc = __builtin_amdgcn_mfma_f32_16x16x32_bf16(                       \
            ap, vone, lacc, 0, 0, 0);                                         \
        _Pragma("unroll")                                                     \
        for (int t = 0; t < 4; ++t) {                                         \
            bf16x8 bv = *(const bf16x8*)                                      \
                &Vs[CUR][(t * 16 + l15) * 64 + ((quad * 8 + 32 * k) ^ swz)];  \
            O[t] = __builtin_amdgcn_mfma_f32_16x16x32_bf16(                   \
                ap, bv, O[t], 0, 0, 0);                                       \
        }                                                                     \
    }                                                                         \
    __syncthreads();                                                          \
} while (0)

__global__ __launch_bounds__(256)
void attn_kernel(const u16* __restrict__ Qb, const u16* __restrict__ Kb,
                 const u16* __restrict__ Vt, u16* __restrict__ AO)
{
    __shared__ __align__(16) u16 Ks[2][64 * 64];
    __shared__ __align__(16) u16 Vs[2][64 * 64];
    __shared__ __align__(16) u16 Ps[4][16 * 64];   // wave-private P tiles

    const int tid  = threadIdx.x;
    const int lane = tid & 63;
    const int wid  = tid >> 6;
    const int l15  = lane & 15;
    const int quad = lane >> 4;
    const int swz  = (l15 & 7) << 3;   // XOR swizzle for frag reads/P ops

    // XCD swizzle: xcd = f&7 -> bh in {3*xcd .. 3*xcd+2}; 96 blocks/XCD.
    const int f  = blockIdx.x;
    const int i  = f >> 3;
    const int bh = (f & 7) * 3 + (i >> 5);   // 0..23
    const int qt = i & 31;                   // 0..31

    const u16* Qg = Qb + ((size_t)bh * NSEQ + qt * 64) * HD;
    const u16* Kg = Kb + (size_t)bh * NSEQ * HD;
    const u16* Vg = Vt + (size_t)bh * HD * NSEQ;   // [64][2048]

    const int r0 = tid >> 3;
    const int cs = ((tid & 7) ^ (r0 & 7)) << 3;    // inverse-swizzled src col

    // Q fragments straight from global (rows are 128B; one-time read)
    bf16x8 aq[2];
    aq[0] = *(const bf16x8*)&Qg[(wid * 16 + l15) * HD + quad * 8];
    aq[1] = *(const bf16x8*)&Qg[(wid * 16 + l15) * HD + quad * 8 + 32];

    union { u16 s[8]; bf16x8 v; } oneu;
#pragma unroll
    for (int ii = 0; ii < 8; ++ii) oneu.s[ii] = 0x3f80;   // bf16 1.0
    const bf16x8 vone = oneu.v;

    f32x4 O[4];
#pragma unroll
    for (int t = 0; t < 4; ++t) O[t] = (f32x4){0.f, 0.f, 0.f, 0.f};
    f32x4 lacc = (f32x4){0.f, 0.f, 0.f, 0.f};   // softmax denominator rows

    u16* Pw = Ps[wid];

    STAGE_KV(0, 0);
    __syncthreads();

    for (int kt = 0; kt < NSEQ / 64; kt += 2) {
        ATTN_STEP(kt, 0, 1);
        ATTN_STEP(kt + 1, 1, 0);
    }

    float inv4[4];
#pragma unroll
    for (int r = 0; r < 4; ++r) inv4[r] = 1.0f / lacc[r];

    const int b = bh / NH, h = bh % NH;
#pragma unroll
    for (int r = 0; r < 4; ++r) {
        size_t orow = (size_t)b * NSEQ + qt * 64 + wid * 16 + quad * 4 + r;
#pragma unroll
        for (int t = 0; t < 4; ++t)
            AO[orow * CDIM + h * HD + t * 16 + l15] = f2bf(O[t][r] * inv4[r]);
    }
}

// ---------------------------------------------------------------------------
// Kernel 3: out = AO @ Wprojb^T + bias, bf16 MFMA. R13: both operands now
// bf16 -> gload_lds dbuf staging, ONE barrier per K-step (removes the
// serial per-iteration latency exposure of the 2-barrier register-staged
// version). 64x64 tiles, grid 768, LDS 32KB -> 5 blocks/CU. XCD-pinned
// m-slices (AO slice 786KB + W 1.2MB per XCD, L2-resident).
// ---------------------------------------------------------------------------
#define PROJ_STAGE(BUF, kt_) do {                                             \
    _Pragma("unroll")                                                         \
    for (int it = 0; it < 2; ++it) {                                          \
        int ch = tid + 256 * it; int rr = ch >> 3;                            \
        int sc = ((ch & 7) ^ (rr & 7)) << 3;                                  \
        GLD16(Ag + (size_t)(m0 + rr) * CDIM + (kt_) + sc, &S[BUF][ch * 8]);   \
        GLD16(Wg + (size_t)(n0 + rr) * CDIM + (kt_) + sc,                     \
              &S[BUF][4096 + ch * 8]);                                        \
    }                                                                         \
} while (0)

__global__ __launch_bounds__(256)
void proj_kernel(const u16* __restrict__ Ag, const u16* __restrict__ Wg,
                 const float* __restrict__ bias, float* __restrict__ out)
{
    __shared__ __align__(16) u16 S[2][8192];   // [buf][A 64x64 | B 64x64]
    const int tid  = threadIdx.x;
    const int lane = tid & 63;
    const int wid  = tid >> 6;
    const int l15  = lane & 15;
    const int quad = lane >> 4;
    const int swz  = (l15 & 7) << 3;
    const int wr = wid >> 1, wc = wid & 1;

    // XCD-pinned m-slices (768 = 8 XCD x 8 m x 12 n), n-major within XCD
    const int f  = blockIdx.x;
    const int xc = f & 7;
    const int s  = f >> 3;                  // 0..95
    const int m0 = (xc * 8 + (s & 7)) * 64;
    const int n0 = (s >> 3) * 64;

    f32x4 acc[2][2];
#pragma unroll
    for (int mi = 0; mi < 2; ++mi)
#pragma unroll
        for (int ni = 0; ni < 2; ++ni)
            acc[mi][ni] = (f32x4){0.f, 0.f, 0.f, 0.f};

    PROJ_STAGE(0, 0);
    __syncthreads();

    int cur = 0;
    for (int kt = 0; kt < CDIM; kt += 64) {
        if (kt + 64 < CDIM) PROJ_STAGE(cur ^ 1, kt + 64);

#pragma unroll
        for (int k = 0; k < 2; ++k) {
            bf16x8 af[2], bf[2];
#pragma unroll
            for (int mi = 0; mi < 2; ++mi)
                af[mi] = *(const bf16x8*)
                    &S[cur][(wr * 32 + mi * 16 + l15) * 64
                            + ((quad * 8 + 32 * k) ^ swz)];
#pragma unroll
            for (int ni = 0; ni < 2; ++ni)
                bf[ni] = *(const bf16x8*)
                    &S[cur][4096 + (wc * 32 + ni * 16 + l15) * 64
                            + ((quad * 8 + 32 * k) ^ swz)];
#pragma unroll
            for (int mi = 0; mi < 2; ++mi)
#pragma unroll
                for (int ni = 0; ni < 2; ++ni)
                    acc[mi][ni] = __builtin_amdgcn_mfma_f32_16x16x32_bf16(
                        af[mi], bf[ni], acc[mi][ni], 0, 0, 0);
        }
        __syncthreads();
        cur ^= 1;
    }

#pragma unroll
    for (int ni = 0; ni < 2; ++ni) {
        int col = n0 + wc * 32 + ni * 16 + l15;
        float bb = bias[col];
#pragma unroll
        for (int mi = 0; mi < 2; ++mi) {
            int rw = m0 + wr * 32 + mi * 16 + quad * 4;
#pragma unroll
            for (int r = 0; r < 4; ++r)
                out[(size_t)(rw + r) * CDIM + col] = acc[mi][ni][r] + bb;
        }
    }
}

// ---------------------------------------------------------------------------
extern "C" void kernel_launch(void* const* d_in, const int* in_sizes, int n_in,
                              void* d_out, int out_size, void* d_ws,
                              size_t ws_size, hipStream_t stream)
{
    const float* X     = (const float*)d_in[0];   // [2, 2048, 768]
    const float* Wqkv  = (const float*)d_in[1];   // [2304, 768]
    const float* Wproj = (const float*)d_in[2];   // [768, 768]
    const float* bias  = (const float*)d_in[3];   // [768]
    float* out = (float*)d_out;                   // [2, 2048, 768]

    const size_t per_buf = (size_t)NB * NH * NSEQ * HD;   // 3145728
    u16* Qb  = (u16*)d_ws;
    u16* Kb  = Qb + per_buf;
    u16* Vb  = Kb + per_buf;                      // [B,H,64,N]
    u16* XAO = Vb + per_buf;      // Xb (conv->qkv), then AO (attn->proj)
    u16* Wqb = XAO + per_buf;                     // [2304,768] bf16
    u16* Wpb = Wqb + (size_t)3 * CDIM * CDIM;     // [768,768] bf16

    conv_kernel<<<dim3(2688), 256, 0, stream>>>(X, Wqkv, Wproj, XAO, Wqb, Wpb);
    qkv_mfma_kernel<<<dim3(1152), 256, 0, stream>>>(XAO, Wqb, Qb, Kb, Vb);
    attn_kernel<<<dim3(768), 256, 0, stream>>>(Qb, Kb, Vb, XAO);
    proj_kernel<<<dim3(768), 256, 0, stream>>>(XAO, Wpb, bias, out);
}

// Round 6
// 144.228 us; speedup vs baseline: 2.0430x; 1.0249x over previous
//
#include <hip/hip_runtime.h>
#include <math.h>

#define NSEQ 2048
#define CDIM 768
#define NH   12
#define HD   64
#define NB   2

typedef unsigned short u16;
typedef __attribute__((ext_vector_type(8))) short bf16x8;   // 8 bf16 = 4 VGPRs
typedef __attribute__((ext_vector_type(4))) float f32x4;
typedef __attribute__((ext_vector_type(8))) float f32x8;
typedef __attribute__((ext_vector_type(4))) __bf16 bf16x4t;
typedef __attribute__((ext_vector_type(8))) __bf16 bf16x8t;

// fp32 -> bf16 round-to-nearest-even (scalar epilogue paths)
__device__ __forceinline__ u16 f2bf(float x) {
    unsigned int u = __float_as_uint(x);
    u += 0x7fffu + ((u >> 16) & 1u);
    return (u16)(u >> 16);
}

// pack 8 fp32 -> 8 bf16 via compiler-generated v_cvt_pk_bf16_f32
__device__ __forceinline__ uint4 pack8(float4 a, float4 b) {
    f32x8 v = {a.x, a.y, a.z, a.w, b.x, b.y, b.z, b.w};
    union { bf16x8t t; uint4 u; } o;
    o.t = __builtin_convertvector(v, bf16x8t);
    return o.u;
}

// raw v_exp_f32 (2^x). R14: log2e baked into Wq scale -> softmax uses
// exp2 directly, deleting the 16 v_mul/iter hipcc emits for __expf.
__device__ __forceinline__ float fexp2(float x) {
#if __has_builtin(__builtin_amdgcn_exp2f)
    return __builtin_amdgcn_exp2f(x);
#else
    float r; asm("v_exp_f32 %0, %1" : "=v"(r) : "v"(x)); return r;
#endif
}

#define LSTR 72    // epilogue scratch stride (u16)
#define ESTR 136   // V-epilogue transpose tile stride (u16): 128+8

// async global->LDS, 16B per lane, LDS dest = wave-uniform base + lane*16
#define GLD16(gp, lp) __builtin_amdgcn_global_load_lds( \
    (__attribute__((address_space(1))) void*)(const void*)(gp), \
    (__attribute__((address_space(3))) void*)(void*)(lp), 16, 0, 0)

// ---------------------------------------------------------------------------
// Kernel 0: one-shot fp32->bf16 conversion of X, Wqkv, Wproj.
// R14: Wq rows scaled by 0.125 * log2(e) so attn's softmax can use raw
// v_exp_f32 (exp2) with no per-element multiply. RoPE is linear -> the
// scale commutes with rotation; 2^(S*log2e) == exp(S) mathematically.
// 688128 chunks of 8 floats, exactly 2688x256 threads, no bounds check.
// ---------------------------------------------------------------------------
__global__ __launch_bounds__(256)
void conv_kernel(const float* __restrict__ Xf, const float* __restrict__ Wqkv,
                 const float* __restrict__ Wproj, u16* __restrict__ Xb,
                 u16* __restrict__ Wqb, u16* __restrict__ Wpb)
{
    const int c = blockIdx.x * 256 + threadIdx.x;   // 0..688127
    const float* src; u16* dst; int lc; float scl = 1.0f;
    if (c < 393216)      { src = Xf;    dst = Xb;  lc = c; }
    else if (c < 614400) { src = Wqkv;  dst = Wqb; lc = c - 393216;
                           if (lc < 73728) scl = 0.18033688011112042f; }
    else                 { src = Wproj; dst = Wpb; lc = c - 614400; }
    float4 a = *(const float4*)&src[(size_t)lc * 8];
    float4 b = *(const float4*)&src[(size_t)lc * 8 + 4];
    a.x *= scl; a.y *= scl; a.z *= scl; a.w *= scl;
    b.x *= scl; b.y *= scl; b.z *= scl; b.w *= scl;
    *(uint4*)&dst[(size_t)lc * 8] = pack8(a, b);
}

// ---------------------------------------------------------------------------
// Kernel 1: qkv = Xb @ Wqkvb^T, pure bf16 MFMA (R13-proven). Both operands
// staged via global_load_lds (linear LDS + source-side XOR swizzle),
// double-buffered, ONE barrier per K-step. Tile 128(M)x64(N), 4 waves each
// own 32 tokens x the block's single head-col. n-major-within-XCD swizzle.
// Q,K: [B,H,N,64]; V: [B,H,64,N]. RoPE fused (scales pre-baked in Wq).
// ---------------------------------------------------------------------------
#define QKV_STAGE(BUF, kt_) do {                                              \
    _Pragma("unroll")                                                         \
    for (int it = 0; it < 4; ++it) {                                          \
        int ch = tid + 256 * it; int rr = ch >> 3;                            \
        int sc = ((ch & 7) ^ (rr & 7)) << 3;                                  \
        GLD16(Xg + (size_t)(m0 + rr) * CDIM + (kt_) + sc, &S[BUF][ch * 8]);   \
    }                                                                         \
    _Pragma("unroll")                                                         \
    for (int it = 0; it < 2; ++it) {                                          \
        int ch = tid + 256 * it; int rr = ch >> 3;                            \
        int sc = ((ch & 7) ^ (rr & 7)) << 3;                                  \
        GLD16(Wg + (size_t)(n0 + rr) * CDIM + (kt_) + sc,                     \
              &S[BUF][8192 + ch * 8]);                                        \
    }                                                                         \
} while (0)

__global__ __launch_bounds__(256)
void qkv_mfma_kernel(const u16* __restrict__ Xg, const u16* __restrict__ Wg,
                     u16* __restrict__ Qb, u16* __restrict__ Kb,
                     u16* __restrict__ Vb)
{
    __shared__ __align__(16) u16 S[2][12288];   // [buf][A 128x64 | B 64x64]

    const int tid  = threadIdx.x;
    const int lane = tid & 63;
    const int wid  = tid >> 6;
    const int l15  = lane & 15;
    const int quad = lane >> 4;
    const int swz  = (l15 & 7) << 3;

    // n-major-within-XCD bijective swizzle (1152 = 8 XCD x 4 m x 36 n)
    const int f  = blockIdx.x;
    const int xc = f & 7;
    const int s  = f >> 3;                  // 0..143
    const int m0 = (xc * 4 + (s & 3)) * 128;
    const int n0 = (s >> 2) * 64;

    f32x4 acc[2][4];
#pragma unroll
    for (int mi = 0; mi < 2; ++mi)
#pragma unroll
        for (int ni = 0; ni < 4; ++ni)
            acc[mi][ni] = (f32x4){0.f, 0.f, 0.f, 0.f};

    QKV_STAGE(0, 0);
    __syncthreads();

    int cur = 0;
    for (int kt = 0; kt < CDIM; kt += 64) {
        if (kt + 64 < CDIM) QKV_STAGE(cur ^ 1, kt + 64);

#pragma unroll
        for (int k = 0; k < 2; ++k) {
            bf16x8 af[2];
#pragma unroll
            for (int mi = 0; mi < 2; ++mi)
                af[mi] = *(const bf16x8*)
                    &S[cur][(wid * 32 + mi * 16 + l15) * 64
                            + ((quad * 8 + 32 * k) ^ swz)];
#pragma unroll
            for (int ni = 0; ni < 4; ++ni) {
                bf16x8 bfr = *(const bf16x8*)
                    &S[cur][8192 + (ni * 16 + l15) * 64
                            + ((quad * 8 + 32 * k) ^ swz)];
#pragma unroll
                for (int mi = 0; mi < 2; ++mi)
                    acc[mi][ni] = __builtin_amdgcn_mfma_f32_16x16x32_bf16(
                        af[mi], bfr, acc[mi][ni], 0, 0, 0);
            }
        }
        __syncthreads();
        cur ^= 1;
    }

    // Epilogue. token row = wid*32 + mi*16 + quad*4 + r; col = ni*16 + l15.
    const int bi      = m0 >> 11;
    const int tokbase = m0 & 2047;
    const int nbase   = tokbase + wid * 32;
    const int sel     = n0 / CDIM;           // 0=q,1=k,2=v
    const int h       = (n0 % CDIM) >> 6;
    u16* Sf = &S[0][0];

    if (sel == 2) {
        u16* Ew = Sf;                        // shared 64(d) x 128(tok) tile
#pragma unroll
        for (int ni = 0; ni < 4; ++ni)
#pragma unroll
            for (int mi = 0; mi < 2; ++mi)
#pragma unroll
                for (int r = 0; r < 4; ++r)
                    Ew[(ni * 16 + l15) * ESTR + wid * 32 + mi * 16 + quad * 4 + r]
                        = f2bf(acc[mi][ni][r]);
        __syncthreads();
        u16* dst = Vb + (size_t)(bi * NH + h) * HD * NSEQ;   // [64][2048]
#pragma unroll
        for (int it = 0; it < 4; ++it) {
            int idx = tid + 256 * it;          // 1024 chunks = 64 rows x 16
            int dd  = idx >> 4;
            int c8  = (idx & 15) << 3;
            *(uint4*)&dst[(size_t)dd * NSEQ + tokbase + c8] =
                *(const uint4*)&Ew[dd * ESTR + c8];
        }
    } else {
        u16* dst = ((sel == 0) ? Qb : Kb) + (size_t)(bi * NH + h) * NSEQ * HD;
        u16* Ew = Sf + wid * 32 * LSTR;        // wave-private 32x72 tile
#pragma unroll
        for (int ni = 0; ni < 4; ++ni) {
            int dd = ni * 16 + l15;
            float invf = expf(-0.14391156831212787f * (float)(dd & ~1));
#pragma unroll
            for (int mi = 0; mi < 2; ++mi) {
                f32x4 val = acc[mi][ni];
#pragma unroll
                for (int r = 0; r < 4; ++r) {
                    float e = val[r];
                    float p = __shfl_xor(e, 1);    // pair partner (col^1)
                    int n = nbase + mi * 16 + quad * 4 + r;
                    float sv, cv;
                    __sincosf((float)n * invf, &sv, &cv);
                    float o = (dd & 1) ? (e * cv + p * sv)
                                       : (e * cv - p * sv);
                    Ew[(mi * 16 + quad * 4 + r) * LSTR + dd] = f2bf(o);
                }
            }
        }
#pragma unroll
        for (int it = 0; it < 4; ++it) {
            int ch  = lane + 64 * it;          // 32 rows x 8 chunks
            int tr  = ch >> 3;
            int gc8 = (ch & 7) << 3;
            *(uint4*)&dst[(size_t)(nbase + tr) * HD + gc8] =
                *(const uint4*)&Ew[tr * LSTR + gc8];
        }
    }
}

// ---------------------------------------------------------------------------
// Kernel 2: flash attention, bf16 MFMA. R14 (on the proven R1 structure):
// (a) softmax via raw v_exp_f32 (log2e pre-baked in Wq) — removes 16 VALU
// muls/iter from the critical chain (VALUBusy was the top pipe at 40%);
// (b) s_setprio(1) around both MFMA clusters (T5: attn blocks run at
// independent phases, m191 +4-7%). Structure otherwise frozen.
// ---------------------------------------------------------------------------
#define STAGE_KV(BUF, kt_) do {                                               \
    GLD16(Kg + ((size_t)(((kt_) << 6) + r0) * HD + cs),                       \
          &Ks[BUF][wid * 512]);                                               \
    GLD16(Kg + ((size_t)(((kt_) << 6) + r0 + 32) * HD + cs),                  \
          &Ks[BUF][wid * 512 + 2048]);                                        \
    GLD16(Vg + ((size_t)r0 * NSEQ + ((kt_) << 6) + cs),                       \
          &Vs[BUF][wid * 512]);                                               \
    GLD16(Vg + ((size_t)(r0 + 32) * NSEQ + ((kt_) << 6) + cs),                \
          &Vs[BUF][wid * 512 + 2048]);                                        \
} while (0)

#define ATTN_STEP(kt_, CUR, NXT) do {                                         \
    if ((kt_) + 1 < NSEQ / 64) STAGE_KV(NXT, (kt_) + 1);                      \
    f32x4 sacc[4];                                                            \
    _Pragma("unroll")                                                         \
    for (int mt = 0; mt < 4; ++mt) sacc[mt] = (f32x4){0.f, 0.f, 0.f, 0.f};    \
    __builtin_amdgcn_s_setprio(1);                                            \
    _Pragma("unroll")                                                         \
    for (int k = 0; k < 2; ++k) {                                             \
        _Pragma("unroll")                                                     \
        for (int mt = 0; mt < 4; ++mt) {                                      \
            bf16x8 ak = *(const bf16x8*)                                      \
                &Ks[CUR][(mt * 16 + l15) * 64 + ((quad * 8 + 32 * k) ^ swz)]; \
            sacc[mt] = __builtin_amdgcn_mfma_f32_16x16x32_bf16(               \
                ak, aq[k], sacc[mt], 0, 0, 0);                                \
        }                                                                     \
    }                                                                         \
    __builtin_amdgcn_s_setprio(0);                                            \
    _Pragma("unroll")                                                         \
    for (int mt = 0; mt < 4; ++mt) {                                          \
        f32x4 ev;                                                             \
        _Pragma("unroll")                                                     \
        for (int r = 0; r < 4; ++r) ev[r] = fexp2(sacc[mt][r]);               \
        bf16x4t pbk = __builtin_convertvector(ev, bf16x4t);                   \
        *(bf16x4t*)&Pw[l15 * 64 + ((mt * 16 + quad * 4) ^ swz)] = pbk;        \
    }                                                                         \
    __builtin_amdgcn_s_setprio(1);                                            \
    _Pragma("unroll")                                                         \
    for (int k = 0; k < 2; ++k) {                                             \
        bf16x8 ap = *(const bf16x8*)                                          \
            &Pw[l15 * 64 + ((quad * 8 + 32 * k) ^ swz)];                      \
        lacc = __builtin_amdgcn_mfma_f32_16x16x32_bf16(                       \
            ap, vone, lacc, 0, 0, 0);                                         \
        _Pragma("unroll")                                                     \
        for (int t = 0; t < 4; ++t) {                                         \
            bf16x8 bv = *(const bf16x8*)                                      \
                &Vs[CUR][(t * 16 + l15) * 64 + ((quad * 8 + 32 * k) ^ swz)];  \
            O[t] = __builtin_amdgcn_mfma_f32_16x16x32_bf16(                   \
                ap, bv, O[t], 0, 0, 0);                                       \
        }                                                                     \
    }                                                                         \
    __builtin_amdgcn_s_setprio(0);                                            \
    __syncthreads();                                                          \
} while (0)

__global__ __launch_bounds__(256)
void attn_kernel(const u16* __restrict__ Qb, const u16* __restrict__ Kb,
                 const u16* __restrict__ Vt, u16* __restrict__ AO)
{
    __shared__ __align__(16) u16 Ks[2][64 * 64];
    __shared__ __align__(16) u16 Vs[2][64 * 64];
    __shared__ __align__(16) u16 Ps[4][16 * 64];   // wave-private P tiles

    const int tid  = threadIdx.x;
    const int lane = tid & 63;
    const int wid  = tid >> 6;
    const int l15  = lane & 15;
    const int quad = lane >> 4;
    const int swz  = (l15 & 7) << 3;   // XOR swizzle for frag reads/P ops

    // XCD swizzle: xcd = f&7 -> bh in {3*xcd .. 3*xcd+2}; 96 blocks/XCD.
    const int f  = blockIdx.x;
    const int i  = f >> 3;
    const int bh = (f & 7) * 3 + (i >> 5);   // 0..23
    const int qt = i & 31;                   // 0..31

    const u16* Qg = Qb + ((size_t)bh * NSEQ + qt * 64) * HD;
    const u16* Kg = Kb + (size_t)bh * NSEQ * HD;
    const u16* Vg = Vt + (size_t)bh * HD * NSEQ;   // [64][2048]

    const int r0 = tid >> 3;
    const int cs = ((tid & 7) ^ (r0 & 7)) << 3;    // inverse-swizzled src col

    // Q fragments straight from global (rows are 128B; one-time read)
    bf16x8 aq[2];
    aq[0] = *(const bf16x8*)&Qg[(wid * 16 + l15) * HD + quad * 8];
    aq[1] = *(const bf16x8*)&Qg[(wid * 16 + l15) * HD + quad * 8 + 32];

    union { u16 s[8]; bf16x8 v; } oneu;
#pragma unroll
    for (int ii = 0; ii < 8; ++ii) oneu.s[ii] = 0x3f80;   // bf16 1.0
    const bf16x8 vone = oneu.v;

    f32x4 O[4];
#pragma unroll
    for (int t = 0; t < 4; ++t) O[t] = (f32x4){0.f, 0.f, 0.f, 0.f};
    f32x4 lacc = (f32x4){0.f, 0.f, 0.f, 0.f};   // softmax denominator rows

    u16* Pw = Ps[wid];

    STAGE_KV(0, 0);
    __syncthreads();

    for (int kt = 0; kt < NSEQ / 64; kt += 2) {
        ATTN_STEP(kt, 0, 1);
        ATTN_STEP(kt + 1, 1, 0);
    }

    float inv4[4];
#pragma unroll
    for (int r = 0; r < 4; ++r) inv4[r] = 1.0f / lacc[r];

    const int b = bh / NH, h = bh % NH;
#pragma unroll
    for (int r = 0; r < 4; ++r) {
        size_t orow = (size_t)b * NSEQ + qt * 64 + wid * 16 + quad * 4 + r;
#pragma unroll
        for (int t = 0; t < 4; ++t)
            AO[orow * CDIM + h * HD + t * 16 + l15] = f2bf(O[t][r] * inv4[r]);
    }
}

// ---------------------------------------------------------------------------
// Kernel 3: out = AO @ Wprojb^T + bias, bf16 MFMA (R13-proven). gload_lds
// dbuf staging, ONE barrier per K-step. 64x64 tiles, grid 768, XCD-pinned
// m-slices.
// ---------------------------------------------------------------------------
#define PROJ_STAGE(BUF, kt_) do {                                             \
    _Pragma("unroll")                                                         \
    for (int it = 0; it < 2; ++it) {                                          \
        int ch = tid + 256 * it; int rr = ch >> 3;                            \
        int sc = ((ch & 7) ^ (rr & 7)) << 3;                                  \
        GLD16(Ag + (size_t)(m0 + rr) * CDIM + (kt_) + sc, &S[BUF][ch * 8]);   \
        GLD16(Wg + (size_t)(n0 + rr) * CDIM + (kt_) + sc,                     \
              &S[BUF][4096 + ch * 8]);                                        \
    }                                                                         \
} while (0)

__global__ __launch_bounds__(256)
void proj_kernel(const u16* __restrict__ Ag, const u16* __restrict__ Wg,
                 const float* __restrict__ bias, float* __restrict__ out)
{
    __shared__ __align__(16) u16 S[2][8192];   // [buf][A 64x64 | B 64x64]
    const int tid  = threadIdx.x;
    const int lane = tid & 63;
    const int wid  = tid >> 6;
    const int l15  = lane & 15;
    const int quad = lane >> 4;
    const int swz  = (l15 & 7) << 3;
    const int wr = wid >> 1, wc = wid & 1;

    // XCD-pinned m-slices (768 = 8 XCD x 8 m x 12 n), n-major within XCD
    const int f  = blockIdx.x;
    const int xc = f & 7;
    const int s  = f >> 3;                  // 0..95
    const int m0 = (xc * 8 + (s & 7)) * 64;
    const int n0 = (s >> 3) * 64;

    f32x4 acc[2][2];
#pragma unroll
    for (int mi = 0; mi < 2; ++mi)
#pragma unroll
        for (int ni = 0; ni < 2; ++ni)
            acc[mi][ni] = (f32x4){0.f, 0.f, 0.f, 0.f};

    PROJ_STAGE(0, 0);
    __syncthreads();

    int cur = 0;
    for (int kt = 0; kt < CDIM; kt += 64) {
        if (kt + 64 < CDIM) PROJ_STAGE(cur ^ 1, kt + 64);

#pragma unroll
        for (int k = 0; k < 2; ++k) {
            bf16x8 af[2], bf[2];
#pragma unroll
            for (int mi = 0; mi < 2; ++mi)
                af[mi] = *(const bf16x8*)
                    &S[cur][(wr * 32 + mi * 16 + l15) * 64
                            + ((quad * 8 + 32 * k) ^ swz)];
#pragma unroll
            for (int ni = 0; ni < 2; ++ni)
                bf[ni] = *(const bf16x8*)
                    &S[cur][4096 + (wc * 32 + ni * 16 + l15) * 64
                            + ((quad * 8 + 32 * k) ^ swz)];
#pragma unroll
            for (int mi = 0; mi < 2; ++mi)
#pragma unroll
                for (int ni = 0; ni < 2; ++ni)
                    acc[mi][ni] = __builtin_amdgcn_mfma_f32_16x16x32_bf16(
                        af[mi], bf[ni], acc[mi][ni], 0, 0, 0);
        }
        __syncthreads();
        cur ^= 1;
    }

#pragma unroll
    for (int ni = 0; ni < 2; ++ni) {
        int col = n0 + wc * 32 + ni * 16 + l15;
        float bb = bias[col];
#pragma unroll
        for (int mi = 0; mi < 2; ++mi) {
            int rw = m0 + wr * 32 + mi * 16 + quad * 4;
#pragma unroll
            for (int r = 0; r < 4; ++r)
                out[(size_t)(rw + r) * CDIM + col] = acc[mi][ni][r] + bb;
        }
    }
}

// ---------------------------------------------------------------------------
extern "C" void kernel_launch(void* const* d_in, const int* in_sizes, int n_in,
                              void* d_out, int out_size, void* d_ws,
                              size_t ws_size, hipStream_t stream)
{
    const float* X     = (const float*)d_in[0];   // [2, 2048, 768]
    const float* Wqkv  = (const float*)d_in[1];   // [2304, 768]
    const float* Wproj = (const float*)d_in[2];   // [768, 768]
    const float* bias  = (const float*)d_in[3];   // [768]
    float* out = (float*)d_out;                   // [2, 2048, 768]

    const size_t per_buf = (size_t)NB * NH * NSEQ * HD;   // 3145728
    u16* Qb  = (u16*)d_ws;
    u16* Kb  = Qb + per_buf;
    u16* Vb  = Kb + per_buf;                      // [B,H,64,N]
    u16* XAO = Vb + per_buf;      // Xb (conv->qkv), then AO (attn->proj)
    u16* Wqb = XAO + per_buf;                     // [2304,768] bf16
    u16* Wpb = Wqb + (size_t)3 * CDIM * CDIM;     // [768,768] bf16

    conv_kernel<<<dim3(2688), 256, 0, stream>>>(X, Wqkv, Wproj, XAO, Wqb, Wpb);
    qkv_mfma_kernel<<<dim3(1152), 256, 0, stream>>>(XAO, Wqb, Qb, Kb, Vb);
    attn_kernel<<<dim3(768), 256, 0, stream>>>(Qb, Kb, Vb, XAO);
    proj_kernel<<<dim3(768), 256, 0, stream>>>(XAO, Wpb, bias, out);
}